// Round 2
// baseline (4008.076 us; speedup 1.0000x reference)
//
#include <hip/hip_runtime.h>

#define N_Q 8192
#define N_K 16384
#define C_DIM 256
#define BQ 128     // queries per block
#define BK 256     // codes per k-tile
#define CC 16      // c-chunk size
#define KTILES 8   // k-tiles per block (block covers BK*KTILES = 2048 codes)
#define NCH 8      // k-chunks across grid
#define XS_STRIDE 132
#define ES_STRIDE 260

// ---------------------------------------------------------------------------
// Precompute: esq[k], xsq[q] (EXACT same summation order as the passing R1
// kernel: 4 partials of 64 sequential fmaf, then ((p0+p1)+p2)+p3), and init
// packed argmin buffer to all-ones (done every launch -> deterministic).
// ---------------------------------------------------------------------------
__global__ __launch_bounds__(256) void vq_pre_kernel(
    const float* __restrict__ hidden, const float* __restrict__ cb,
    float* __restrict__ esq, float* __restrict__ xsq,
    unsigned long long* __restrict__ packed) {
  int k = blockIdx.x * 256 + threadIdx.x;
  if (k < N_K) {
    const float4* row = reinterpret_cast<const float4*>(cb + (size_t)k * C_DIM);
    float s = 0.f;
#pragma unroll 8
    for (int c4 = 0; c4 < C_DIM / 4; ++c4) {
      float4 v = row[c4];
      s = fmaf(v.x, v.x, s);
      s = fmaf(v.y, v.y, s);
      s = fmaf(v.z, v.z, s);
      s = fmaf(v.w, v.w, s);
    }
    esq[k] = s;
  }
  if (k < N_Q) {
    int b = k >> 10, hw = k & 1023;
    const float* hp = hidden + (size_t)b * C_DIM * 1024 + hw;
    float p0 = 0.f, p1 = 0.f, p2 = 0.f, p3 = 0.f;
    for (int c = 0; c < 64; ++c) { float v = hp[(c)*1024];       p0 = fmaf(v, v, p0); }
    for (int c = 0; c < 64; ++c) { float v = hp[(64 + c) * 1024];  p1 = fmaf(v, v, p1); }
    for (int c = 0; c < 64; ++c) { float v = hp[(128 + c) * 1024]; p2 = fmaf(v, v, p2); }
    for (int c = 0; c < 64; ++c) { float v = hp[(192 + c) * 1024]; p3 = fmaf(v, v, p3); }
    xsq[k] = ((p0 + p1) + p2) + p3;
    packed[k] = ~0ull;
  }
}

// ---------------------------------------------------------------------------
// Main: 512 threads = 16 qgroups x 32 kgroups, 8x8 register tile.
// Block tile 128q x 256k, C streamed in chunks of 16 through small LDS
// (xs c-major from hidden's natural (c,hw) layout; es transposed to [c][k],
// stride 260 -> analyzed 2-way bank aliasing = free). Register prefetch of
// the next chunk's global loads overlaps compute. Strict ascending-c fmaf
// chain per acc preserves bit-exact R1 semantics. Cross-block reduce via
// packed (dbits,k) u64 atomicMin (d>0 always; min pack = first-index ties).
// ---------------------------------------------------------------------------
__global__ __launch_bounds__(512, 4) void vq_main_kernel(
    const float* __restrict__ hidden, const float* __restrict__ cb,
    const float* __restrict__ esq, const float* __restrict__ xsq,
    unsigned long long* __restrict__ packed) {
  __shared__ __align__(16) float xs[CC][XS_STRIDE];
  __shared__ __align__(16) float es[CC][ES_STRIDE];

  const int tid = threadIdx.x;
  const int bid = blockIdx.x;
  const int kch = bid & 7;        // XCD-aligned k-chunk (round-robin xcd)
  const int qt = bid >> 3;
  const int q0 = qt * BQ;
  const int b = q0 >> 10;
  const int hw0 = q0 & 1023;
  const float* hb = hidden + (size_t)b * C_DIM * 1024 + hw0;

  const int qg = tid >> 5;  // 0..15
  const int kg = tid & 31;  // 0..31

  // staging maps
  const int cx = tid >> 5;        // 0..15 (c within chunk for x-stage)
  const int q4 = tid & 31;        // float4 index along q
  const int f0 = tid;             // e-stage element 0
  const int f1 = tid + 512;       // e-stage element 1
  const int ke0 = f0 >> 2, c4e0 = f0 & 3;
  const int ke1 = f1 >> 2, c4e1 = f1 & 3;

  float bd[8];
  int bk[8];
#pragma unroll
  for (int i = 0; i < 8; ++i) { bd[i] = 3.4e38f; bk[i] = 0x7fffffff; }

  for (int kt = 0; kt < KTILES; ++kt) {
    const int kt0 = kch * (BK * KTILES) + kt * BK;

    float acc[8][8];
#pragma unroll
    for (int i = 0; i < 8; ++i)
#pragma unroll
      for (int j = 0; j < 8; ++j) acc[i][j] = 0.f;

    // prefetch chunk 0
    float4 xreg = *reinterpret_cast<const float4*>(&hb[cx * 1024 + q4 * 4]);
    float4 ereg0 = *reinterpret_cast<const float4*>(
        &cb[(size_t)(kt0 + ke0) * C_DIM + c4e0 * 4]);
    float4 ereg1 = *reinterpret_cast<const float4*>(
        &cb[(size_t)(kt0 + ke1) * C_DIM + c4e1 * 4]);

    for (int cc = 0; cc < C_DIM / CC; ++cc) {
      __syncthreads();  // previous chunk fully consumed
      *reinterpret_cast<float4*>(&xs[cx][q4 * 4]) = xreg;
      es[c4e0 * 4 + 0][ke0] = ereg0.x;
      es[c4e0 * 4 + 1][ke0] = ereg0.y;
      es[c4e0 * 4 + 2][ke0] = ereg0.z;
      es[c4e0 * 4 + 3][ke0] = ereg0.w;
      es[c4e1 * 4 + 0][ke1] = ereg1.x;
      es[c4e1 * 4 + 1][ke1] = ereg1.y;
      es[c4e1 * 4 + 2][ke1] = ereg1.z;
      es[c4e1 * 4 + 3][ke1] = ereg1.w;
      __syncthreads();

      if (cc + 1 < C_DIM / CC) {  // prefetch next chunk (overlaps compute)
        const int c0n = (cc + 1) * CC;
        xreg = *reinterpret_cast<const float4*>(
            &hb[(c0n + cx) * 1024 + q4 * 4]);
        ereg0 = *reinterpret_cast<const float4*>(
            &cb[(size_t)(kt0 + ke0) * C_DIM + c0n + c4e0 * 4]);
        ereg1 = *reinterpret_cast<const float4*>(
            &cb[(size_t)(kt0 + ke1) * C_DIM + c0n + c4e1 * 4]);
      }

#pragma unroll
      for (int c = 0; c < CC; ++c) {
        float4 xa = *reinterpret_cast<const float4*>(&xs[c][qg * 8]);
        float4 xb = *reinterpret_cast<const float4*>(&xs[c][qg * 8 + 4]);
        float4 ea = *reinterpret_cast<const float4*>(&es[c][kg * 8]);
        float4 eb = *reinterpret_cast<const float4*>(&es[c][kg * 8 + 4]);
#pragma unroll
        for (int i = 0; i < 8; ++i) {
          float xv = (i < 4) ? ((i == 0) ? xa.x : (i == 1) ? xa.y : (i == 2) ? xa.z : xa.w)
                             : ((i == 4) ? xb.x : (i == 5) ? xb.y : (i == 6) ? xb.z : xb.w);
          acc[i][0] = fmaf(xv, ea.x, acc[i][0]);
          acc[i][1] = fmaf(xv, ea.y, acc[i][1]);
          acc[i][2] = fmaf(xv, ea.z, acc[i][2]);
          acc[i][3] = fmaf(xv, ea.w, acc[i][3]);
          acc[i][4] = fmaf(xv, eb.x, acc[i][4]);
          acc[i][5] = fmaf(xv, eb.y, acc[i][5]);
          acc[i][6] = fmaf(xv, eb.z, acc[i][6]);
          acc[i][7] = fmaf(xv, eb.w, acc[i][7]);
        }
      }
    }

    // epilogue: d = fl(fl(xsq+esq) - 2*acc), running first-index argmin
    float4 ea = *reinterpret_cast<const float4*>(&esq[kt0 + kg * 8]);
    float4 eb = *reinterpret_cast<const float4*>(&esq[kt0 + kg * 8 + 4]);
    float4 qa = *reinterpret_cast<const float4*>(&xsq[q0 + qg * 8]);
    float4 qb = *reinterpret_cast<const float4*>(&xsq[q0 + qg * 8 + 4]);
    float eqv[8] = {ea.x, ea.y, ea.z, ea.w, eb.x, eb.y, eb.z, eb.w};
    float xqv[8] = {qa.x, qa.y, qa.z, qa.w, qb.x, qb.y, qb.z, qb.w};
#pragma unroll
    for (int i = 0; i < 8; ++i) {
#pragma unroll
      for (int j = 0; j < 8; ++j) {
        float t1 = xqv[i] + eqv[j];
        float d = t1 - 2.0f * acc[i][j];
        int k = kt0 + kg * 8 + j;
        if (d < bd[i]) { bd[i] = d; bk[i] = k; }
      }
    }
  }

  // reduce across the 32 kgroups (within-wave: lanes l, same qg = l>>5)
#pragma unroll
  for (int i = 0; i < 8; ++i) {
    unsigned long long v =
        ((unsigned long long)__float_as_uint(bd[i]) << 32) | (unsigned)bk[i];
#pragma unroll
    for (int m = 1; m <= 16; m <<= 1) {
      unsigned long long o = __shfl_xor(v, m, 32);
      if (o < v) v = o;
    }
    if (kg == 0) atomicMin(&packed[q0 + qg * 8 + i], v);
  }
}

// ---------------------------------------------------------------------------
// Unpack: low 32 bits of the packed min = argmin index.
// ---------------------------------------------------------------------------
__global__ __launch_bounds__(256) void vq_final_kernel(
    const unsigned long long* __restrict__ packed, int* __restrict__ out) {
  int n = blockIdx.x * 256 + threadIdx.x;
  if (n < N_Q) out[n] = (int)(unsigned)(packed[n] & 0xffffffffull);
}

extern "C" void kernel_launch(void* const* d_in, const int* in_sizes, int n_in,
                              void* d_out, int out_size, void* d_ws,
                              size_t ws_size, hipStream_t stream) {
  const float* hidden = (const float*)d_in[0];  // (8,1,256,32,32) fp32
  const float* cb = (const float*)d_in[1];      // (16384,256) fp32
  float* esq = (float*)d_ws;                                   // 64 KB
  float* xsq = (float*)((char*)d_ws + 65536);                  // 32 KB
  unsigned long long* packed =
      (unsigned long long*)((char*)d_ws + 65536 + 32768);      // 64 KB
  int* out = (int*)d_out;

  vq_pre_kernel<<<dim3(N_K / 256), dim3(256), 0, stream>>>(hidden, cb, esq,
                                                           xsq, packed);
  vq_main_kernel<<<dim3((N_Q / BQ) * NCH), dim3(512), 0, stream>>>(
      hidden, cb, esq, xsq, packed);
  vq_final_kernel<<<dim3(N_Q / 256), dim3(256), 0, stream>>>(packed, out);
}

// Round 3
// 1515.137 us; speedup vs baseline: 2.6454x; 2.6454x over previous
//
#include <hip/hip_runtime.h>

#define N_Q 8192
#define N_K 16384
#define C_DIM 256
#define BM 128
#define BN 128
#define BK 64
#define NGRAN 256   // 64-code granules
#define GRAN 64
#define MARGIN 8e-4f

typedef __attribute__((ext_vector_type(8))) short short8;
typedef __attribute__((ext_vector_type(4))) float f32x4;
typedef unsigned long long u64;

__device__ inline unsigned short f2bf(float f) {  // RNE fp32->bf16 (finite)
  unsigned u = __float_as_uint(f);
  return (unsigned short)((u + 0x7fffu + ((u >> 16) & 1u)) >> 16);
}

__device__ inline void gl_lds16(const void* g, void* l) {
  __builtin_amdgcn_global_load_lds(
      (const __attribute__((address_space(1))) unsigned int*)g,
      (__attribute__((address_space(3))) unsigned int*)l, 16, 0, 0);
}

// ===========================================================================
// pre_x: transpose hidden -> xt fp32 [8192][256] + xb bf16; xsq with the
// R1/R2-validated exact order (4 partials of 64 seq fmaf, ((p0+p1)+p2)+p3);
// init packed approx-min.
// ===========================================================================
__global__ __launch_bounds__(256) void vq_pre_x(
    const float* __restrict__ hidden, float* __restrict__ xt,
    unsigned short* __restrict__ xb, float* __restrict__ xsq,
    u64* __restrict__ packed) {
  int q = blockIdx.x * 256 + threadIdx.x;
  int b = q >> 10, hw = q & 1023;
  const float* hp = hidden + (size_t)b * (C_DIM * 1024) + hw;
  float* xo = xt + (size_t)q * C_DIM;
  unsigned short* bo = xb + (size_t)q * C_DIM;
  float p0 = 0.f, p1 = 0.f, p2 = 0.f, p3 = 0.f;
  for (int c = 0; c < 64; ++c) { float v = hp[c * 1024];         xo[c] = v;       bo[c] = f2bf(v);       p0 = fmaf(v, v, p0); }
  for (int c = 0; c < 64; ++c) { float v = hp[(64 + c) * 1024];  xo[64 + c] = v;  bo[64 + c] = f2bf(v);  p1 = fmaf(v, v, p1); }
  for (int c = 0; c < 64; ++c) { float v = hp[(128 + c) * 1024]; xo[128 + c] = v; bo[128 + c] = f2bf(v); p2 = fmaf(v, v, p2); }
  for (int c = 0; c < 64; ++c) { float v = hp[(192 + c) * 1024]; xo[192 + c] = v; bo[192 + c] = f2bf(v); p3 = fmaf(v, v, p3); }
  xsq[q] = ((p0 + p1) + p2) + p3;
  packed[q] = ~0ull;
}

// esq (exact R1 order) + eb bf16
__global__ __launch_bounds__(256) void vq_pre_e(
    const float* __restrict__ cb, unsigned short* __restrict__ eb,
    float* __restrict__ esq) {
  int k = blockIdx.x * 256 + threadIdx.x;
  const float4* row = (const float4*)(cb + (size_t)k * C_DIM);
  unsigned short* eo = eb + (size_t)k * C_DIM;
  float s = 0.f;
  for (int c4 = 0; c4 < C_DIM / 4; ++c4) {
    float4 v = row[c4];
    s = fmaf(v.x, v.x, s); s = fmaf(v.y, v.y, s);
    s = fmaf(v.z, v.z, s); s = fmaf(v.w, v.w, s);
    eo[c4 * 4 + 0] = f2bf(v.x); eo[c4 * 4 + 1] = f2bf(v.y);
    eo[c4 * 4 + 2] = f2bf(v.z); eo[c4 * 4 + 3] = f2bf(v.w);
  }
  esq[k] = s;
}

// ===========================================================================
// Prefilter GEMM: 128x128 tile, BK=64, global_load_lds double-buffer, 4 waves
// (2x2 quadrants of 64x64), 16x16x32 bf16 MFMA. k-slot layout-agnostic: A and
// B frags use the identical contiguous-8 slot->c mapping, so any bijective HW
// k-permutation cancels in the dot product. Epilogue: per-(row, 64-granule)
// approx-min -> mins[], global packed atomicMin.
// ===========================================================================
__global__ __launch_bounds__(256) void vq_gemm(
    const unsigned short* __restrict__ xb, const unsigned short* __restrict__ eb,
    const float* __restrict__ xsq, const float* __restrict__ esq,
    float* __restrict__ mins, u64* __restrict__ packed) {
  __shared__ __align__(16) unsigned short As[2][BM * BK];
  __shared__ __align__(16) unsigned short Bs[2][BN * BK];

  const int tid = threadIdx.x;
  const int wid = tid >> 6;
  const int lane = tid & 63;

  // XCD-aware mapping: each XCD owns a contiguous 16-nb slice (1MB of eb)
  int bidx = blockIdx.x;
  int xcd = bidx & 7;
  int idx = bidx >> 3;
  int nb = xcd * 16 + (idx >> 6);  // 0..127
  int qb = idx & 63;
  const int q0 = qb * BM;
  const int n0 = nb * BN;

  const int wr = wid >> 1, wc = wid & 1;
  const int lrow = lane & 15;
  const int lkhi = lane >> 4;
  const int srow = lane >> 3;
  const int sseg = lane & 7;

  auto stage = [&](int kt, int bf) {
#pragma unroll
    for (int i = 0; i < 4; ++i) {
      int r0 = (wid * 4 + i) * 8;  // 8 rows = 1KB per wave-issue, linear LDS
      gl_lds16(xb + (size_t)(q0 + r0 + srow) * C_DIM + kt * BK + sseg * 8,
               (void*)((char*)&As[bf][0] + (size_t)r0 * BK * 2));
      gl_lds16(eb + (size_t)(n0 + r0 + srow) * C_DIM + kt * BK + sseg * 8,
               (void*)((char*)&Bs[bf][0] + (size_t)r0 * BK * 2));
    }
  };

  f32x4 acc[4][4];
#pragma unroll
  for (int i = 0; i < 4; ++i)
#pragma unroll
    for (int j = 0; j < 4; ++j) acc[i][j] = (f32x4){0.f, 0.f, 0.f, 0.f};

  stage(0, 0);
  asm volatile("s_waitcnt vmcnt(0)" ::: "memory");
  __syncthreads();

  for (int kt = 0; kt < C_DIM / BK; ++kt) {
    int bf = kt & 1;
    if (kt + 1 < C_DIM / BK) stage(kt + 1, bf ^ 1);
#pragma unroll
    for (int kk = 0; kk < 2; ++kk) {
      short8 a[4], b[4];
#pragma unroll
      for (int mi = 0; mi < 4; ++mi)
        a[mi] = *(const short8*)((const char*)&As[bf][0] +
                 (size_t)((wr * 64 + mi * 16 + lrow) * BK + kk * 32 + lkhi * 8) * 2);
#pragma unroll
      for (int ni = 0; ni < 4; ++ni)
        b[ni] = *(const short8*)((const char*)&Bs[bf][0] +
                 (size_t)((wc * 64 + ni * 16 + lrow) * BK + kk * 32 + lkhi * 8) * 2);
#pragma unroll
      for (int mi = 0; mi < 4; ++mi)
#pragma unroll
        for (int ni = 0; ni < 4; ++ni)
          acc[mi][ni] = __builtin_amdgcn_mfma_f32_16x16x32_bf16(
              a[mi], b[ni], acc[mi][ni], 0, 0, 0);
    }
    asm volatile("s_waitcnt vmcnt(0)" ::: "memory");
    __syncthreads();
  }

  // epilogue: d~ = (xsq+esq) - 2*acc; per-granule min via 16-lane shfl reduce
  float eqv[4];
#pragma unroll
  for (int ni = 0; ni < 4; ++ni) eqv[ni] = esq[n0 + wc * 64 + ni * 16 + lrow];
  const int g = nb * 2 + wc;  // this wave's 64-code granule
#pragma unroll
  for (int mi = 0; mi < 4; ++mi) {
#pragma unroll
    for (int j = 0; j < 4; ++j) {
      int row = q0 + wr * 64 + mi * 16 + lkhi * 4 + j;
      float xq = xsq[row];
      u64 bst = ~0ull;
#pragma unroll
      for (int ni = 0; ni < 4; ++ni) {
        float d = (xq + eqv[ni]) - 2.0f * acc[mi][ni][j];
        int k = n0 + wc * 64 + ni * 16 + lrow;
        u64 p = ((u64)__float_as_uint(d) << 32) | (unsigned)k;
        if (p < bst) bst = p;
      }
#pragma unroll
      for (int m = 1; m <= 8; m <<= 1) {
        u64 o = __shfl_xor(bst, m);
        if (o < bst) bst = o;
      }
      if (lrow == 0) {
        mins[(size_t)row * NGRAN + g] = __uint_as_float((unsigned)(bst >> 32));
        atomicMin(&packed[row], bst);
      }
    }
  }
}

// ===========================================================================
// Exact rescore of flagged granules: R1's exact fmaf chain + packed min
// (first-index ties). One wave per query.
// ===========================================================================
__global__ __launch_bounds__(64) void vq_rescore(
    const float* __restrict__ xt, const float* __restrict__ cb,
    const float* __restrict__ xsq, const float* __restrict__ esq,
    const float* __restrict__ mins, const u64* __restrict__ packed,
    int* __restrict__ out) {
  const int q = blockIdx.x;
  const int t = threadIdx.x;  // 0..63
  const float thr = __uint_as_float((unsigned)(packed[q] >> 32)) + MARGIN;
  const float4* xv4 = (const float4*)(xt + (size_t)q * C_DIM);
  const float xq = xsq[q];
  u64 best = ~0ull;
  for (int g = 0; g < NGRAN; ++g) {
    if (mins[(size_t)q * NGRAN + g] <= thr) {
      int k = g * GRAN + t;
      const float4* er = (const float4*)(cb + (size_t)k * C_DIM);
      float m = 0.f;
      for (int c4 = 0; c4 < C_DIM / 4; ++c4) {
        float4 xv = xv4[c4], ev = er[c4];
        m = fmaf(xv.x, ev.x, m); m = fmaf(xv.y, ev.y, m);
        m = fmaf(xv.z, ev.z, m); m = fmaf(xv.w, ev.w, m);
      }
      float d = (xq + esq[k]) - 2.0f * m;
      u64 p = ((u64)__float_as_uint(d) << 32) | (unsigned)k;
      if (p < best) best = p;
    }
  }
#pragma unroll
  for (int m = 1; m <= 32; m <<= 1) {
    u64 o = __shfl_xor(best, m);
    if (o < best) best = o;
  }
  if (t == 0) out[q] = (int)(unsigned)(best & 0xffffffffull);
}

// ===========================================================================
// Fallback (R1, known-pass, ~1338us) if ws is too small for the MFMA path.
// ===========================================================================
#define TQ 64
#define TK 64
#define R1_NCH 8
#define R1_KCHUNK (N_K / R1_NCH)

__global__ __launch_bounds__(256) void r1_esq(const float* __restrict__ cb,
                                              float* __restrict__ esq) {
  int k = blockIdx.x * blockDim.x + threadIdx.x;
  if (k >= N_K) return;
  const float4* row = reinterpret_cast<const float4*>(cb + (size_t)k * C_DIM);
  float s = 0.f;
#pragma unroll 8
  for (int c4 = 0; c4 < C_DIM / 4; ++c4) {
    float4 v = row[c4];
    s = fmaf(v.x, v.x, s); s = fmaf(v.y, v.y, s);
    s = fmaf(v.z, v.z, s); s = fmaf(v.w, v.w, s);
  }
  esq[k] = s;
}

__global__ __launch_bounds__(256) void r1_main(
    const float* __restrict__ hidden, const float* __restrict__ cb,
    const float* __restrict__ esq, float* __restrict__ ws_d,
    int* __restrict__ ws_k) {
  __shared__ __align__(16) float xs[C_DIM][TQ + 4];
  __shared__ __align__(16) float es[TK][C_DIM + 4];
  __shared__ float xsq_part[4][TQ];
  __shared__ float xsq[TQ];
  __shared__ float red_d[16][TQ];
  __shared__ int red_k[16][TQ];
  const int tid = threadIdx.x;
  const int q0 = blockIdx.x * TQ;
  const int b = q0 >> 10;
  const int hw0 = q0 & 1023;
  const float* hb = hidden + (size_t)b * (C_DIM * 1024) + hw0;
  for (int idx = tid; idx < C_DIM * TQ; idx += 256) {
    int c = idx >> 6, q = idx & 63;
    xs[c][q] = hb[c * 1024 + q];
  }
  __syncthreads();
  {
    int q = tid & 63, part = tid >> 6, cbase = part * 64;
    float s = 0.f;
    for (int c = 0; c < 64; ++c) { float v = xs[cbase + c][q]; s = fmaf(v, v, s); }
    xsq_part[part][q] = s;
  }
  __syncthreads();
  if (tid < TQ)
    xsq[tid] = ((xsq_part[0][tid] + xsq_part[1][tid]) + xsq_part[2][tid]) + xsq_part[3][tid];
  __syncthreads();
  const int qt = tid & 15, kt = tid >> 4;
  float xsq_r[4];
#pragma unroll
  for (int i = 0; i < 4; ++i) xsq_r[i] = xsq[qt * 4 + i];
  float bd[4]; int bk[4];
#pragma unroll
  for (int i = 0; i < 4; ++i) { bd[i] = 3.4e38f; bk[i] = 0x7fffffff; }
  const int kbegin = blockIdx.y * R1_KCHUNK;
  for (int kt0 = kbegin; kt0 < kbegin + R1_KCHUNK; kt0 += TK) {
    __syncthreads();
    for (int idx = tid; idx < TK * (C_DIM / 4); idx += 256) {
      int kk = idx >> 6, c4 = idx & 63;
      float4 v = reinterpret_cast<const float4*>(cb + (size_t)(kt0 + kk) * C_DIM)[c4];
      es[kk][c4 * 4 + 0] = v.x; es[kk][c4 * 4 + 1] = v.y;
      es[kk][c4 * 4 + 2] = v.z; es[kk][c4 * 4 + 3] = v.w;
    }
    __syncthreads();
    float acc[4][4];
#pragma unroll
    for (int i = 0; i < 4; ++i)
#pragma unroll
      for (int j = 0; j < 4; ++j) acc[i][j] = 0.f;
    for (int c4 = 0; c4 < C_DIM; c4 += 4) {
      float4 xv0 = *reinterpret_cast<const float4*>(&xs[c4 + 0][qt * 4]);
      float4 xv1 = *reinterpret_cast<const float4*>(&xs[c4 + 1][qt * 4]);
      float4 xv2 = *reinterpret_cast<const float4*>(&xs[c4 + 2][qt * 4]);
      float4 xv3 = *reinterpret_cast<const float4*>(&xs[c4 + 3][qt * 4]);
      float xq0[4] = {xv0.x, xv0.y, xv0.z, xv0.w};
      float xq1[4] = {xv1.x, xv1.y, xv1.z, xv1.w};
      float xq2[4] = {xv2.x, xv2.y, xv2.z, xv2.w};
      float xq3[4] = {xv3.x, xv3.y, xv3.z, xv3.w};
      float4 ev[4];
#pragma unroll
      for (int j = 0; j < 4; ++j)
        ev[j] = *reinterpret_cast<const float4*>(&es[kt * 4 + j][c4]);
#pragma unroll
      for (int i = 0; i < 4; ++i) {
#pragma unroll
        for (int j = 0; j < 4; ++j) {
          float a = acc[i][j];
          a = fmaf(xq0[i], ev[j].x, a);
          a = fmaf(xq1[i], ev[j].y, a);
          a = fmaf(xq2[i], ev[j].z, a);
          a = fmaf(xq3[i], ev[j].w, a);
          acc[i][j] = a;
        }
      }
    }
#pragma unroll
    for (int j = 0; j < 4; ++j) {
      int k = kt0 + kt * 4 + j;
      float eq = esq[k];
#pragma unroll
      for (int i = 0; i < 4; ++i) {
        float t1 = xsq_r[i] + eq;
        float d = t1 - 2.0f * acc[i][j];
        if (d < bd[i]) { bd[i] = d; bk[i] = k; }
      }
    }
  }
#pragma unroll
  for (int i = 0; i < 4; ++i) {
    red_d[kt][qt * 4 + i] = bd[i];
    red_k[kt][qt * 4 + i] = bk[i];
  }
  __syncthreads();
  if (tid < TQ) {
    float d = red_d[0][tid]; int kb = red_k[0][tid];
    for (int t = 1; t < 16; ++t) {
      float dn = red_d[t][tid]; int kn = red_k[t][tid];
      if (dn < d || (dn == d && kn < kb)) { d = dn; kb = kn; }
    }
    int q = q0 + tid;
    ws_d[(size_t)q * R1_NCH + blockIdx.y] = d;
    ws_k[(size_t)q * R1_NCH + blockIdx.y] = kb;
  }
}

__global__ __launch_bounds__(256) void r1_final(
    const float* __restrict__ ws_d, const int* __restrict__ ws_k,
    int* __restrict__ out) {
  int n = blockIdx.x * blockDim.x + threadIdx.x;
  if (n >= N_Q) return;
  const float* dp = ws_d + (size_t)n * R1_NCH;
  const int* kp = ws_k + (size_t)n * R1_NCH;
  float d = dp[0]; int kb = kp[0];
#pragma unroll
  for (int j = 1; j < R1_NCH; ++j) {
    float dn = dp[j]; int kn = kp[j];
    if (dn < d || (dn == d && kn < kb)) { d = dn; kb = kn; }
  }
  out[n] = kb;
}

extern "C" void kernel_launch(void* const* d_in, const int* in_sizes, int n_in,
                              void* d_out, int out_size, void* d_ws,
                              size_t ws_size, hipStream_t stream) {
  const float* hidden = (const float*)d_in[0];
  const float* cb = (const float*)d_in[1];
  int* out = (int*)d_out;

  const size_t MB = 1024 * 1024;
  const size_t off_xb = 0;                 // 4MB bf16 [8192][256]
  const size_t off_eb = 4 * MB;            // 8MB bf16 [16384][256]
  const size_t off_xt = 12 * MB;           // 8MB fp32 [8192][256]
  const size_t off_xsq = 20 * MB;          // 32KB
  const size_t off_esq = 20 * MB + 65536;  // 64KB
  const size_t off_pk = 20 * MB + 196608;  // 64KB u64
  const size_t off_mins = 21 * MB;         // 8MB fp32 [8192][256]
  const size_t NEED = 29 * MB;

  if (ws_size >= NEED) {
    unsigned short* xb = (unsigned short*)((char*)d_ws + off_xb);
    unsigned short* eb = (unsigned short*)((char*)d_ws + off_eb);
    float* xt = (float*)((char*)d_ws + off_xt);
    float* xsq = (float*)((char*)d_ws + off_xsq);
    float* esq = (float*)((char*)d_ws + off_esq);
    u64* packed = (u64*)((char*)d_ws + off_pk);
    float* mins = (float*)((char*)d_ws + off_mins);

    vq_pre_x<<<dim3(N_Q / 256), dim3(256), 0, stream>>>(hidden, xt, xb, xsq, packed);
    vq_pre_e<<<dim3(N_K / 256), dim3(256), 0, stream>>>(cb, eb, esq);
    vq_gemm<<<dim3((N_Q / BM) * (N_K / BN)), dim3(256), 0, stream>>>(
        xb, eb, xsq, esq, mins, packed);
    vq_rescore<<<dim3(N_Q), dim3(64), 0, stream>>>(xt, cb, xsq, esq, mins, packed, out);
  } else {
    float* esq = (float*)d_ws;
    float* ws_d = (float*)((char*)d_ws + 65536);
    int* ws_k = (int*)((char*)d_ws + 65536 + N_Q * R1_NCH * 4);
    r1_esq<<<dim3(N_K / 256), dim3(256), 0, stream>>>(cb, esq);
    r1_main<<<dim3(N_Q / TQ, R1_NCH), dim3(256), 0, stream>>>(hidden, cb, esq, ws_d, ws_k);
    r1_final<<<dim3(N_Q / 256), dim3(256), 0, stream>>>(ws_d, ws_k, out);
  }
}

// Round 5
// 655.084 us; speedup vs baseline: 6.1184x; 2.3129x over previous
//
#include <hip/hip_runtime.h>

#define N_Q 8192
#define N_K 16384
#define C_DIM 256
#define BM 128
#define BN 128
#define BK 64
#define NGRAN 256   // 64-code granules
#define GRAN 64
#define MARGIN 8e-4f
#define QSPLIT 8    // query-splits per granule in rescore
#define QPW ((N_Q / QSPLIT) / 4)  // queries per wave = 256

typedef __attribute__((ext_vector_type(8))) short short8;
typedef __attribute__((ext_vector_type(4))) float f32x4;
typedef unsigned long long u64;

__device__ inline unsigned short f2bf(float f) {  // RNE fp32->bf16 (finite)
  unsigned u = __float_as_uint(f);
  return (unsigned short)((u + 0x7fffu + ((u >> 16) & 1u)) >> 16);
}

__device__ inline void gl_lds16(const void* g, void* l) {
  __builtin_amdgcn_global_load_lds(
      (const __attribute__((address_space(1))) unsigned int*)g,
      (__attribute__((address_space(3))) unsigned int*)l, 16, 0, 0);
}

// ===========================================================================
// pre_x: transpose hidden -> xt fp32 + xb bf16; xsq exact R1 order; init
// packed (approx min) & packed2 (exact min).
// ===========================================================================
__global__ __launch_bounds__(256) void vq_pre_x(
    const float* __restrict__ hidden, float* __restrict__ xt,
    unsigned short* __restrict__ xb, float* __restrict__ xsq,
    u64* __restrict__ packed, u64* __restrict__ packed2) {
  int q = blockIdx.x * 256 + threadIdx.x;
  int b = q >> 10, hw = q & 1023;
  const float* hp = hidden + (size_t)b * (C_DIM * 1024) + hw;
  float* xo = xt + (size_t)q * C_DIM;
  unsigned short* bo = xb + (size_t)q * C_DIM;
  float p0 = 0.f, p1 = 0.f, p2 = 0.f, p3 = 0.f;
  for (int c = 0; c < 64; ++c) { float v = hp[c * 1024];         xo[c] = v;       bo[c] = f2bf(v);       p0 = fmaf(v, v, p0); }
  for (int c = 0; c < 64; ++c) { float v = hp[(64 + c) * 1024];  xo[64 + c] = v;  bo[64 + c] = f2bf(v);  p1 = fmaf(v, v, p1); }
  for (int c = 0; c < 64; ++c) { float v = hp[(128 + c) * 1024]; xo[128 + c] = v; bo[128 + c] = f2bf(v); p2 = fmaf(v, v, p2); }
  for (int c = 0; c < 64; ++c) { float v = hp[(192 + c) * 1024]; xo[192 + c] = v; bo[192 + c] = f2bf(v); p3 = fmaf(v, v, p3); }
  xsq[q] = ((p0 + p1) + p2) + p3;
  packed[q] = ~0ull;
  packed2[q] = ~0ull;
}

// esq (exact R1 order) + eb bf16
__global__ __launch_bounds__(256) void vq_pre_e(
    const float* __restrict__ cb, unsigned short* __restrict__ eb,
    float* __restrict__ esq) {
  int k = blockIdx.x * 256 + threadIdx.x;
  const float4* row = (const float4*)(cb + (size_t)k * C_DIM);
  unsigned short* eo = eb + (size_t)k * C_DIM;
  float s = 0.f;
  for (int c4 = 0; c4 < C_DIM / 4; ++c4) {
    float4 v = row[c4];
    s = fmaf(v.x, v.x, s); s = fmaf(v.y, v.y, s);
    s = fmaf(v.z, v.z, s); s = fmaf(v.w, v.w, s);
    eo[c4 * 4 + 0] = f2bf(v.x); eo[c4 * 4 + 1] = f2bf(v.y);
    eo[c4 * 4 + 2] = f2bf(v.z); eo[c4 * 4 + 3] = f2bf(v.w);
  }
  esq[k] = s;
}

// ===========================================================================
// Prefilter GEMM (R3-verified core): 128x128 tile, BK=64, global_load_lds
// dbuf, 4 waves, 16x16x32 bf16 MFMA. Epilogue: per-(row,granule) approx min
// -> mins_t[g][row] FULL fp32 (transposed for coalesced rescore reads),
// global approx min -> packed via u64 atomicMin.
// ===========================================================================
__global__ __launch_bounds__(256) void vq_gemm(
    const unsigned short* __restrict__ xb, const unsigned short* __restrict__ eb,
    const float* __restrict__ xsq, const float* __restrict__ esq,
    float* __restrict__ mins_t, u64* __restrict__ packed) {
  __shared__ __align__(16) unsigned short As[2][BM * BK];
  __shared__ __align__(16) unsigned short Bs[2][BN * BK];

  const int tid = threadIdx.x;
  const int wid = tid >> 6;
  const int lane = tid & 63;

  int bidx = blockIdx.x;
  int xcd = bidx & 7;
  int idx = bidx >> 3;
  int nb = xcd * 16 + (idx >> 6);  // 0..127
  int qb = idx & 63;
  const int q0 = qb * BM;
  const int n0 = nb * BN;

  const int wr = wid >> 1, wc = wid & 1;
  const int lrow = lane & 15;
  const int lkhi = lane >> 4;
  const int srow = lane >> 3;
  const int sseg = lane & 7;

  auto stage = [&](int kt, int bf) {
#pragma unroll
    for (int i = 0; i < 4; ++i) {
      int r0 = (wid * 4 + i) * 8;
      gl_lds16(xb + (size_t)(q0 + r0 + srow) * C_DIM + kt * BK + sseg * 8,
               (void*)((char*)&As[bf][0] + (size_t)r0 * BK * 2));
      gl_lds16(eb + (size_t)(n0 + r0 + srow) * C_DIM + kt * BK + sseg * 8,
               (void*)((char*)&Bs[bf][0] + (size_t)r0 * BK * 2));
    }
  };

  f32x4 acc[4][4];
#pragma unroll
  for (int i = 0; i < 4; ++i)
#pragma unroll
    for (int j = 0; j < 4; ++j) acc[i][j] = (f32x4){0.f, 0.f, 0.f, 0.f};

  stage(0, 0);
  asm volatile("s_waitcnt vmcnt(0)" ::: "memory");
  __syncthreads();

  for (int kt = 0; kt < C_DIM / BK; ++kt) {
    int bf = kt & 1;
    if (kt + 1 < C_DIM / BK) stage(kt + 1, bf ^ 1);
#pragma unroll
    for (int kk = 0; kk < 2; ++kk) {
      short8 a[4], b[4];
#pragma unroll
      for (int mi = 0; mi < 4; ++mi)
        a[mi] = *(const short8*)((const char*)&As[bf][0] +
                 (size_t)((wr * 64 + mi * 16 + lrow) * BK + kk * 32 + lkhi * 8) * 2);
#pragma unroll
      for (int ni = 0; ni < 4; ++ni)
        b[ni] = *(const short8*)((const char*)&Bs[bf][0] +
                 (size_t)((wc * 64 + ni * 16 + lrow) * BK + kk * 32 + lkhi * 8) * 2);
#pragma unroll
      for (int mi = 0; mi < 4; ++mi)
#pragma unroll
        for (int ni = 0; ni < 4; ++ni)
          acc[mi][ni] = __builtin_amdgcn_mfma_f32_16x16x32_bf16(
              a[mi], b[ni], acc[mi][ni], 0, 0, 0);
    }
    asm volatile("s_waitcnt vmcnt(0)" ::: "memory");
    __syncthreads();
  }

  float eqv[4];
#pragma unroll
  for (int ni = 0; ni < 4; ++ni) eqv[ni] = esq[n0 + wc * 64 + ni * 16 + lrow];
  const int g = nb * 2 + wc;
#pragma unroll
  for (int mi = 0; mi < 4; ++mi) {
#pragma unroll
    for (int j = 0; j < 4; ++j) {
      int row = q0 + wr * 64 + mi * 16 + lkhi * 4 + j;
      float xq = xsq[row];
      u64 bst = ~0ull;
#pragma unroll
      for (int ni = 0; ni < 4; ++ni) {
        float d = (xq + eqv[ni]) - 2.0f * acc[mi][ni][j];
        int k = n0 + wc * 64 + ni * 16 + lrow;
        u64 p = ((u64)__float_as_uint(d) << 32) | (unsigned)k;
        if (p < bst) bst = p;
      }
#pragma unroll
      for (int m = 1; m <= 8; m <<= 1) {
        u64 o = __shfl_xor(bst, m);
        if (o < bst) bst = o;
      }
      if (lrow == 0) {
        mins_t[(size_t)g * N_Q + row] = __uint_as_float((unsigned)(bst >> 32));
        atomicMin(&packed[row], bst);
      }
    }
  }
}

// ===========================================================================
// Scan-based granule-major exact rescore — NO lists, NO capacity limits.
// Grid (NGRAN, QSPLIT). Block stages its granule's 64 codes fp32 transposed
// [c][code] in LDS; each of 4 waves scans 256 queries: coalesced flag check
// mins_t[g][q] <= thr(q), __ballot, then per set bit all 64 lanes rescore
// (lane=code) with the EXACT R1 fmaf chain; u64 atomicMin -> packed2.
// Flag recomputation is deterministic and lossless -> correctness never
// depends on flag-count distribution.
// ===========================================================================
__global__ __launch_bounds__(256) void vq_rescore_s(
    const float* __restrict__ xt, const float* __restrict__ cb,
    const float* __restrict__ xsq, const float* __restrict__ esq,
    const float* __restrict__ mins_t, const u64* __restrict__ packed,
    u64* __restrict__ packed2) {
  __shared__ float cLDS[C_DIM][GRAN];
  const int g = blockIdx.x;
  const int tid = threadIdx.x;

  {  // stage granule codes transposed: thread t -> code t>>2, c4 seg (t&3)*16
    const int kk = tid >> 2;
    const int seg = tid & 3;
    const float4* row = (const float4*)(cb + (size_t)(g * GRAN + kk) * C_DIM);
#pragma unroll
    for (int i = 0; i < 16; ++i) {
      int c4 = seg * 16 + i;
      float4 v = row[c4];
      cLDS[c4 * 4 + 0][kk] = v.x;
      cLDS[c4 * 4 + 1][kk] = v.y;
      cLDS[c4 * 4 + 2][kk] = v.z;
      cLDS[c4 * 4 + 3][kk] = v.w;
    }
  }
  __syncthreads();

  const int w = tid >> 6;
  const int l = tid & 63;
  const int k = g * GRAN + l;
  const float eq = esq[k];
  const float* mrow = mins_t + (size_t)g * N_Q;
  const int qbase0 = blockIdx.y * (N_Q / QSPLIT) + w * QPW;

  for (int b = 0; b < QPW; b += 64) {
    int q = qbase0 + b + l;
    float thr = __uint_as_float((unsigned)(packed[q] >> 32)) + MARGIN;
    bool f = (mrow[q] <= thr);
    u64 mask = __ballot(f);
    while (mask) {
      int bit = __builtin_ctzll(mask);
      mask &= mask - 1;
      int qq = qbase0 + b + bit;
      const float4* xv4 = (const float4*)(xt + (size_t)qq * C_DIM);
      float m = 0.f;
#pragma unroll 8
      for (int c4 = 0; c4 < C_DIM / 4; ++c4) {
        float4 xv = xv4[c4];  // same addr across lanes -> broadcast
        m = fmaf(xv.x, cLDS[c4 * 4 + 0][l], m);
        m = fmaf(xv.y, cLDS[c4 * 4 + 1][l], m);
        m = fmaf(xv.z, cLDS[c4 * 4 + 2][l], m);
        m = fmaf(xv.w, cLDS[c4 * 4 + 3][l], m);
      }
      float d = (xsq[qq] + eq) - 2.0f * m;
      u64 p = ((u64)__float_as_uint(d) << 32) | (unsigned)k;
#pragma unroll
      for (int s = 1; s <= 32; s <<= 1) {
        u64 o = __shfl_xor(p, s);
        if (o < p) p = o;
      }
      if (l == 0) atomicMin(&packed2[qq], p);
    }
  }
}

__global__ __launch_bounds__(256) void vq_out(const u64* __restrict__ packed2,
                                              int* __restrict__ out) {
  int n = blockIdx.x * 256 + threadIdx.x;
  if (n < N_Q) out[n] = (int)(unsigned)(packed2[n] & 0xffffffffull);
}

// ===========================================================================
// Fallback (R1, known-pass) if ws too small.
// ===========================================================================
#define TQ 64
#define TK 64
#define R1_NCH 8
#define R1_KCHUNK (N_K / R1_NCH)

__global__ __launch_bounds__(256) void r1_esq(const float* __restrict__ cb,
                                              float* __restrict__ esq) {
  int k = blockIdx.x * blockDim.x + threadIdx.x;
  if (k >= N_K) return;
  const float4* row = reinterpret_cast<const float4*>(cb + (size_t)k * C_DIM);
  float s = 0.f;
#pragma unroll 8
  for (int c4 = 0; c4 < C_DIM / 4; ++c4) {
    float4 v = row[c4];
    s = fmaf(v.x, v.x, s); s = fmaf(v.y, v.y, s);
    s = fmaf(v.z, v.z, s); s = fmaf(v.w, v.w, s);
  }
  esq[k] = s;
}

__global__ __launch_bounds__(256) void r1_main(
    const float* __restrict__ hidden, const float* __restrict__ cb,
    const float* __restrict__ esq, float* __restrict__ ws_d,
    int* __restrict__ ws_k) {
  __shared__ __align__(16) float xs[C_DIM][TQ + 4];
  __shared__ __align__(16) float es[TK][C_DIM + 4];
  __shared__ float xsq_part[4][TQ];
  __shared__ float xsq[TQ];
  __shared__ float red_d[16][TQ];
  __shared__ int red_k[16][TQ];
  const int tid = threadIdx.x;
  const int q0 = blockIdx.x * TQ;
  const int b = q0 >> 10;
  const int hw0 = q0 & 1023;
  const float* hb = hidden + (size_t)b * (C_DIM * 1024) + hw0;
  for (int idx = tid; idx < C_DIM * TQ; idx += 256) {
    int c = idx >> 6, q = idx & 63;
    xs[c][q] = hb[c * 1024 + q];
  }
  __syncthreads();
  {
    int q = tid & 63, part = tid >> 6, cbase = part * 64;
    float s = 0.f;
    for (int c = 0; c < 64; ++c) { float v = xs[cbase + c][q]; s = fmaf(v, v, s); }
    xsq_part[part][q] = s;
  }
  __syncthreads();
  if (tid < TQ)
    xsq[tid] = ((xsq_part[0][tid] + xsq_part[1][tid]) + xsq_part[2][tid]) + xsq_part[3][tid];
  __syncthreads();
  const int qt = tid & 15, kt = tid >> 4;
  float xsq_r[4];
#pragma unroll
  for (int i = 0; i < 4; ++i) xsq_r[i] = xsq[qt * 4 + i];
  float bd[4]; int bk[4];
#pragma unroll
  for (int i = 0; i < 4; ++i) { bd[i] = 3.4e38f; bk[i] = 0x7fffffff; }
  const int kbegin = blockIdx.y * R1_KCHUNK;
  for (int kt0 = kbegin; kt0 < kbegin + R1_KCHUNK; kt0 += TK) {
    __syncthreads();
    for (int idx = tid; idx < TK * (C_DIM / 4); idx += 256) {
      int kk = idx >> 6, c4 = idx & 63;
      float4 v = reinterpret_cast<const float4*>(cb + (size_t)(kt0 + kk) * C_DIM)[c4];
      es[kk][c4 * 4 + 0] = v.x; es[kk][c4 * 4 + 1] = v.y;
      es[kk][c4 * 4 + 2] = v.z; es[kk][c4 * 4 + 3] = v.w;
    }
    __syncthreads();
    float acc[4][4];
#pragma unroll
    for (int i = 0; i < 4; ++i)
#pragma unroll
      for (int j = 0; j < 4; ++j) acc[i][j] = 0.f;
    for (int c4 = 0; c4 < C_DIM; c4 += 4) {
      float4 xv0 = *reinterpret_cast<const float4*>(&xs[c4 + 0][qt * 4]);
      float4 xv1 = *reinterpret_cast<const float4*>(&xs[c4 + 1][qt * 4]);
      float4 xv2 = *reinterpret_cast<const float4*>(&xs[c4 + 2][qt * 4]);
      float4 xv3 = *reinterpret_cast<const float4*>(&xs[c4 + 3][qt * 4]);
      float xq0[4] = {xv0.x, xv0.y, xv0.z, xv0.w};
      float xq1[4] = {xv1.x, xv1.y, xv1.z, xv1.w};
      float xq2[4] = {xv2.x, xv2.y, xv2.z, xv2.w};
      float xq3[4] = {xv3.x, xv3.y, xv3.z, xv3.w};
      float4 ev[4];
#pragma unroll
      for (int j = 0; j < 4; ++j)
        ev[j] = *reinterpret_cast<const float4*>(&es[kt * 4 + j][c4]);
#pragma unroll
      for (int i = 0; i < 4; ++i) {
#pragma unroll
        for (int j = 0; j < 4; ++j) {
          float a = acc[i][j];
          a = fmaf(xq0[i], ev[j].x, a);
          a = fmaf(xq1[i], ev[j].y, a);
          a = fmaf(xq2[i], ev[j].z, a);
          a = fmaf(xq3[i], ev[j].w, a);
          acc[i][j] = a;
        }
      }
    }
#pragma unroll
    for (int j = 0; j < 4; ++j) {
      int k = kt0 + kt * 4 + j;
      float eq = esq[k];
#pragma unroll
      for (int i = 0; i < 4; ++i) {
        float t1 = xsq_r[i] + eq;
        float d = t1 - 2.0f * acc[i][j];
        if (d < bd[i]) { bd[i] = d; bk[i] = k; }
      }
    }
  }
#pragma unroll
  for (int i = 0; i < 4; ++i) {
    red_d[kt][qt * 4 + i] = bd[i];
    red_k[kt][qt * 4 + i] = bk[i];
  }
  __syncthreads();
  if (tid < TQ) {
    float d = red_d[0][tid]; int kb = red_k[0][tid];
    for (int t = 1; t < 16; ++t) {
      float dn = red_d[t][tid]; int kn = red_k[t][tid];
      if (dn < d || (dn == d && kn < kb)) { d = dn; kb = kn; }
    }
    int q = q0 + tid;
    ws_d[(size_t)q * R1_NCH + blockIdx.y] = d;
    ws_k[(size_t)q * R1_NCH + blockIdx.y] = kb;
  }
}

__global__ __launch_bounds__(256) void r1_final(
    const float* __restrict__ ws_d, const int* __restrict__ ws_k,
    int* __restrict__ out) {
  int n = blockIdx.x * blockDim.x + threadIdx.x;
  if (n >= N_Q) return;
  const float* dp = ws_d + (size_t)n * R1_NCH;
  const int* kp = ws_k + (size_t)n * R1_NCH;
  float d = dp[0]; int kb = kp[0];
#pragma unroll
  for (int j = 1; j < R1_NCH; ++j) {
    float dn = dp[j]; int kn = kp[j];
    if (dn < d || (dn == d && kn < kb)) { d = dn; kb = kn; }
  }
  out[n] = kb;
}

extern "C" void kernel_launch(void* const* d_in, const int* in_sizes, int n_in,
                              void* d_out, int out_size, void* d_ws,
                              size_t ws_size, hipStream_t stream) {
  const float* hidden = (const float*)d_in[0];
  const float* cb = (const float*)d_in[1];
  int* out = (int*)d_out;

  const size_t MB = 1024 * 1024;
  char* w = (char*)d_ws;
  unsigned short* xb = (unsigned short*)(w);                 // 4MB
  unsigned short* eb = (unsigned short*)(w + 4 * MB);        // 8MB
  float* xt = (float*)(w + 12 * MB);                         // 8MB
  float* xsq = (float*)(w + 20 * MB);                        // 32KB
  float* esq = (float*)(w + 20 * MB + 65536);                // 64KB
  u64* packed = (u64*)(w + 20 * MB + 196608);                // 64KB
  u64* packed2 = (u64*)(w + 20 * MB + 262144);               // 64KB
  float* mins_t = (float*)(w + 21 * MB);                     // 8MB [g][q]
  const size_t NEED = 29 * MB;  // same budget R3 proved available

  if (ws_size >= NEED) {
    vq_pre_x<<<dim3(N_Q / 256), dim3(256), 0, stream>>>(hidden, xt, xb, xsq,
                                                        packed, packed2);
    vq_pre_e<<<dim3(N_K / 256), dim3(256), 0, stream>>>(cb, eb, esq);
    vq_gemm<<<dim3((N_Q / BM) * (N_K / BN)), dim3(256), 0, stream>>>(
        xb, eb, xsq, esq, mins_t, packed);
    vq_rescore_s<<<dim3(NGRAN, QSPLIT), dim3(256), 0, stream>>>(
        xt, cb, xsq, esq, mins_t, packed, packed2);
    vq_out<<<dim3(N_Q / 256), dim3(256), 0, stream>>>(packed2, out);
  } else {
    float* esq_f = (float*)d_ws;
    float* ws_d = (float*)((char*)d_ws + 65536);
    int* ws_k = (int*)((char*)d_ws + 65536 + N_Q * R1_NCH * 4);
    r1_esq<<<dim3(N_K / 256), dim3(256), 0, stream>>>(cb, esq_f);
    r1_main<<<dim3(N_Q / TQ, R1_NCH), dim3(256), 0, stream>>>(hidden, cb, esq_f, ws_d, ws_k);
    r1_final<<<dim3(N_Q / 256), dim3(256), 0, stream>>>(ws_d, ws_k, out);
  }
}

// Round 6
// 606.955 us; speedup vs baseline: 6.6036x; 1.0793x over previous
//
#include <hip/hip_runtime.h>

#define N_Q 8192
#define N_K 16384
#define C_DIM 256
#define BM 256
#define BN 256
#define BK 64
#define NGRAN 256   // 64-code granules
#define GRAN 64
#define MARGIN 8e-4f
#define RQS 4       // query-splits per granule in rescore
#define RQB (N_Q / RQS)  // 2048 queries per rescore block

typedef __attribute__((ext_vector_type(8))) short short8;
typedef __attribute__((ext_vector_type(4))) float f32x4;
typedef unsigned long long u64;

__device__ inline unsigned short f2bf(float f) {  // RNE fp32->bf16 (finite)
  unsigned u = __float_as_uint(f);
  return (unsigned short)((u + 0x7fffu + ((u >> 16) & 1u)) >> 16);
}

__device__ inline void gl_lds16(const void* g, void* l) {
  __builtin_amdgcn_global_load_lds(
      (const __attribute__((address_space(1))) unsigned int*)g,
      (__attribute__((address_space(3))) unsigned int*)l, 16, 0, 0);
}

// ===========================================================================
// pre_x: transpose hidden -> xt fp32 + xb bf16; xsq exact R1 order; init
// packed (approx min) & packed2 (exact min).
// ===========================================================================
__global__ __launch_bounds__(256) void vq_pre_x(
    const float* __restrict__ hidden, float* __restrict__ xt,
    unsigned short* __restrict__ xb, float* __restrict__ xsq,
    u64* __restrict__ packed, u64* __restrict__ packed2) {
  int q = blockIdx.x * 256 + threadIdx.x;
  int b = q >> 10, hw = q & 1023;
  const float* hp = hidden + (size_t)b * (C_DIM * 1024) + hw;
  float* xo = xt + (size_t)q * C_DIM;
  unsigned short* bo = xb + (size_t)q * C_DIM;
  float p0 = 0.f, p1 = 0.f, p2 = 0.f, p3 = 0.f;
  for (int c = 0; c < 64; ++c) { float v = hp[c * 1024];         xo[c] = v;       bo[c] = f2bf(v);       p0 = fmaf(v, v, p0); }
  for (int c = 0; c < 64; ++c) { float v = hp[(64 + c) * 1024];  xo[64 + c] = v;  bo[64 + c] = f2bf(v);  p1 = fmaf(v, v, p1); }
  for (int c = 0; c < 64; ++c) { float v = hp[(128 + c) * 1024]; xo[128 + c] = v; bo[128 + c] = f2bf(v); p2 = fmaf(v, v, p2); }
  for (int c = 0; c < 64; ++c) { float v = hp[(192 + c) * 1024]; xo[192 + c] = v; bo[192 + c] = f2bf(v); p3 = fmaf(v, v, p3); }
  xsq[q] = ((p0 + p1) + p2) + p3;
  packed[q] = ~0ull;
  packed2[q] = ~0ull;
}

// esq (exact R1 order) + eb bf16
__global__ __launch_bounds__(256) void vq_pre_e(
    const float* __restrict__ cb, unsigned short* __restrict__ eb,
    float* __restrict__ esq) {
  int k = blockIdx.x * 256 + threadIdx.x;
  const float4* row = (const float4*)(cb + (size_t)k * C_DIM);
  unsigned short* eo = eb + (size_t)k * C_DIM;
  float s = 0.f;
  for (int c4 = 0; c4 < C_DIM / 4; ++c4) {
    float4 v = row[c4];
    s = fmaf(v.x, v.x, s); s = fmaf(v.y, v.y, s);
    s = fmaf(v.z, v.z, s); s = fmaf(v.w, v.w, s);
    eo[c4 * 4 + 0] = f2bf(v.x); eo[c4 * 4 + 1] = f2bf(v.y);
    eo[c4 * 4 + 2] = f2bf(v.z); eo[c4 * 4 + 3] = f2bf(v.w);
  }
  esq[k] = s;
}

// ===========================================================================
// Prefilter GEMM: 256x256 tile, 8 waves (2x4), BK=64 double-buffered via
// global_load_lds, 16x16x32 bf16 MFMA, per-wave 128x64 output (8x4 frags).
// Same frag math + epilogue semantics as the R3/R5-verified 128^2 kernel.
// Wave covers exactly one 64-code granule (g = nb*4 + wc).
// ===========================================================================
__global__ __launch_bounds__(512) void vq_gemm(
    const unsigned short* __restrict__ xb, const unsigned short* __restrict__ eb,
    const float* __restrict__ xsq, const float* __restrict__ esq,
    float* __restrict__ mins_t, u64* __restrict__ packed) {
  __shared__ __align__(16) unsigned short As[2][BM * BK];  // 32KB x2
  __shared__ __align__(16) unsigned short Bs[2][BN * BK];  // 32KB x2

  const int tid = threadIdx.x;
  const int wid = tid >> 6;
  const int lane = tid & 63;

  int bidx = blockIdx.x;
  int xcd = bidx & 7;
  int idx = bidx >> 3;           // 0..255
  int nb = xcd * 8 + (idx >> 5); // 0..63
  int qb = idx & 31;             // 0..31
  const int q0 = qb * BM;
  const int n0 = nb * BN;

  const int wr = wid >> 2, wc = wid & 3;
  const int lrow = lane & 15;
  const int lkhi = lane >> 4;
  const int srow = lane >> 3;
  const int sseg = lane & 7;

  auto stage = [&](int kt, int bf) {
#pragma unroll
    for (int i = 0; i < 4; ++i) {
      int r0 = (wid * 4 + i) * 8;  // 32 wave-issues cover 256 rows
      gl_lds16(xb + (size_t)(q0 + r0 + srow) * C_DIM + kt * BK + sseg * 8,
               (void*)((char*)&As[bf][0] + (size_t)r0 * BK * 2));
      gl_lds16(eb + (size_t)(n0 + r0 + srow) * C_DIM + kt * BK + sseg * 8,
               (void*)((char*)&Bs[bf][0] + (size_t)r0 * BK * 2));
    }
  };

  f32x4 acc[8][4];
#pragma unroll
  for (int i = 0; i < 8; ++i)
#pragma unroll
    for (int j = 0; j < 4; ++j) acc[i][j] = (f32x4){0.f, 0.f, 0.f, 0.f};

  stage(0, 0);
  asm volatile("s_waitcnt vmcnt(0)" ::: "memory");
  __syncthreads();

  for (int kt = 0; kt < C_DIM / BK; ++kt) {
    int bf = kt & 1;
    if (kt + 1 < C_DIM / BK) stage(kt + 1, bf ^ 1);
#pragma unroll
    for (int kk = 0; kk < 2; ++kk) {
      short8 a[8], b[4];
#pragma unroll
      for (int mi = 0; mi < 8; ++mi)
        a[mi] = *(const short8*)((const char*)&As[bf][0] +
                 (size_t)((wr * 128 + mi * 16 + lrow) * BK + kk * 32 + lkhi * 8) * 2);
#pragma unroll
      for (int ni = 0; ni < 4; ++ni)
        b[ni] = *(const short8*)((const char*)&Bs[bf][0] +
                 (size_t)((wc * 64 + ni * 16 + lrow) * BK + kk * 32 + lkhi * 8) * 2);
#pragma unroll
      for (int mi = 0; mi < 8; ++mi)
#pragma unroll
        for (int ni = 0; ni < 4; ++ni)
          acc[mi][ni] = __builtin_amdgcn_mfma_f32_16x16x32_bf16(
              a[mi], b[ni], acc[mi][ni], 0, 0, 0);
    }
    asm volatile("s_waitcnt vmcnt(0)" ::: "memory");
    __syncthreads();
  }

  // epilogue: d~ = (xsq+esq) - 2*acc; per-granule min -> mins_t + packed
  float eqv[4];
#pragma unroll
  for (int ni = 0; ni < 4; ++ni) eqv[ni] = esq[n0 + wc * 64 + ni * 16 + lrow];
  const int g = nb * 4 + wc;
#pragma unroll
  for (int mi = 0; mi < 8; ++mi) {
#pragma unroll
    for (int j = 0; j < 4; ++j) {
      int row = q0 + wr * 128 + mi * 16 + lkhi * 4 + j;
      float xq = xsq[row];
      u64 bst = ~0ull;
#pragma unroll
      for (int ni = 0; ni < 4; ++ni) {
        float d = (xq + eqv[ni]) - 2.0f * acc[mi][ni][j];
        int k = n0 + wc * 64 + ni * 16 + lrow;
        u64 p = ((u64)__float_as_uint(d) << 32) | (unsigned)k;
        if (p < bst) bst = p;
      }
#pragma unroll
      for (int m = 1; m <= 8; m <<= 1) {
        u64 o = __shfl_xor(bst, m);
        if (o < bst) bst = o;
      }
      if (lrow == 0) {
        mins_t[(size_t)g * N_Q + row] = __uint_as_float((unsigned)(bst >> 32));
        atomicMin(&packed[row], bst);
      }
    }
  }
}

// ===========================================================================
// Rescore v2: block = (granule g, query-split). Codes staged ROW-major as
// float4 with XOR slot swizzle (lane l reads cL[l][c4^l] -> ds_read_b128,
// even bank spread). Block-level LDS worklist (scan is lossless; list is
// bounded by the scanned range so it can NEVER overflow). Each wave rescored
// 4 queries concurrently: 4 independent EXACT R1 fmaf chains share each
// e-read (4x ILP, 4x LDS amortization). u64 atomicMin -> packed2.
// ===========================================================================
__global__ __launch_bounds__(256) void vq_rescore_s(
    const float* __restrict__ xt, const float* __restrict__ cb,
    const float* __restrict__ xsq, const float* __restrict__ esq,
    const float* __restrict__ mins_t, const u64* __restrict__ packed,
    u64* __restrict__ packed2) {
  __shared__ __align__(16) float4 cL[GRAN][GRAN];  // 64KB, [code][slot]
  __shared__ int lcnt;
  __shared__ int lbuf[RQB];                        // 8KB, cannot overflow

  const int g = blockIdx.x;
  const int tid = threadIdx.x;
  if (tid == 0) lcnt = 0;

  {  // stage: thread t -> code kk=t>>2, c4 range (t&3)*16..+15, slot c4^kk
    const int kk = tid >> 2;
    const int seg = tid & 3;
    const float4* row = (const float4*)(cb + (size_t)(g * GRAN + kk) * C_DIM);
#pragma unroll
    for (int i = 0; i < 16; ++i) {
      int c4 = seg * 16 + i;
      cL[kk][c4 ^ kk] = row[c4];
    }
  }
  __syncthreads();

  // scan this block's query range; coalesced; append flagged to worklist
  const int qbase = blockIdx.y * RQB;
  for (int c = 0; c < RQB; c += 256) {
    int q = qbase + c + tid;
    float thr = __uint_as_float((unsigned)(packed[q] >> 32)) + MARGIN;
    if (mins_t[(size_t)g * N_Q + q] <= thr) {
      int pos = atomicAdd(&lcnt, 1);
      lbuf[pos] = q;
    }
  }
  __syncthreads();

  const int n = lcnt;
  const int w = tid >> 6;
  const int l = tid & 63;
  const int k = g * GRAN + l;
  const float eq = esq[k];

  for (int i0 = w * 4; i0 < n; i0 += 16) {
    int qi[4];
#pragma unroll
    for (int j = 0; j < 4; ++j) {
      int ii = i0 + j;
      qi[j] = lbuf[ii < n ? ii : n - 1];  // clamp: dup work, identical result
    }
    const float4* x0 = (const float4*)(xt + (size_t)qi[0] * C_DIM);
    const float4* x1 = (const float4*)(xt + (size_t)qi[1] * C_DIM);
    const float4* x2 = (const float4*)(xt + (size_t)qi[2] * C_DIM);
    const float4* x3 = (const float4*)(xt + (size_t)qi[3] * C_DIM);
    float a0 = 0.f, a1 = 0.f, a2 = 0.f, a3 = 0.f;
    for (int c4 = 0; c4 < 64; ++c4) {
      float4 e = cL[l][c4 ^ l];
      float4 v0 = x0[c4];  // broadcast loads (uniform addr per wave)
      float4 v1 = x1[c4];
      float4 v2 = x2[c4];
      float4 v3 = x3[c4];
      a0 = fmaf(v0.x, e.x, a0); a0 = fmaf(v0.y, e.y, a0);
      a0 = fmaf(v0.z, e.z, a0); a0 = fmaf(v0.w, e.w, a0);
      a1 = fmaf(v1.x, e.x, a1); a1 = fmaf(v1.y, e.y, a1);
      a1 = fmaf(v1.z, e.z, a1); a1 = fmaf(v1.w, e.w, a1);
      a2 = fmaf(v2.x, e.x, a2); a2 = fmaf(v2.y, e.y, a2);
      a2 = fmaf(v2.z, e.z, a2); a2 = fmaf(v2.w, e.w, a2);
      a3 = fmaf(v3.x, e.x, a3); a3 = fmaf(v3.y, e.y, a3);
      a3 = fmaf(v3.z, e.z, a3); a3 = fmaf(v3.w, e.w, a3);
    }
    float dv[4] = {a0, a1, a2, a3};
#pragma unroll
    for (int j = 0; j < 4; ++j) {
      float d = (xsq[qi[j]] + eq) - 2.0f * dv[j];
      u64 p = ((u64)__float_as_uint(d) << 32) | (unsigned)k;
#pragma unroll
      for (int s = 1; s <= 32; s <<= 1) {
        u64 o = __shfl_xor(p, s);
        if (o < p) p = o;
      }
      if (l == 0) atomicMin(&packed2[qi[j]], p);
    }
  }
}

__global__ __launch_bounds__(256) void vq_out(const u64* __restrict__ packed2,
                                              int* __restrict__ out) {
  int n = blockIdx.x * 256 + threadIdx.x;
  if (n < N_Q) out[n] = (int)(unsigned)(packed2[n] & 0xffffffffull);
}

// ===========================================================================
// Fallback (R1, known-pass) if ws too small.
// ===========================================================================
#define TQ 64
#define TK 64
#define R1_NCH 8
#define R1_KCHUNK (N_K / R1_NCH)

__global__ __launch_bounds__(256) void r1_esq(const float* __restrict__ cb,
                                              float* __restrict__ esq) {
  int k = blockIdx.x * blockDim.x + threadIdx.x;
  if (k >= N_K) return;
  const float4* row = reinterpret_cast<const float4*>(cb + (size_t)k * C_DIM);
  float s = 0.f;
#pragma unroll 8
  for (int c4 = 0; c4 < C_DIM / 4; ++c4) {
    float4 v = row[c4];
    s = fmaf(v.x, v.x, s); s = fmaf(v.y, v.y, s);
    s = fmaf(v.z, v.z, s); s = fmaf(v.w, v.w, s);
  }
  esq[k] = s;
}

__global__ __launch_bounds__(256) void r1_main(
    const float* __restrict__ hidden, const float* __restrict__ cb,
    const float* __restrict__ esq, float* __restrict__ ws_d,
    int* __restrict__ ws_k) {
  __shared__ __align__(16) float xs[C_DIM][TQ + 4];
  __shared__ __align__(16) float es[TK][C_DIM + 4];
  __shared__ float xsq_part[4][TQ];
  __shared__ float xsq[TQ];
  __shared__ float red_d[16][TQ];
  __shared__ int red_k[16][TQ];
  const int tid = threadIdx.x;
  const int q0 = blockIdx.x * TQ;
  const int b = q0 >> 10;
  const int hw0 = q0 & 1023;
  const float* hb = hidden + (size_t)b * (C_DIM * 1024) + hw0;
  for (int idx = tid; idx < C_DIM * TQ; idx += 256) {
    int c = idx >> 6, q = idx & 63;
    xs[c][q] = hb[c * 1024 + q];
  }
  __syncthreads();
  {
    int q = tid & 63, part = tid >> 6, cbase = part * 64;
    float s = 0.f;
    for (int c = 0; c < 64; ++c) { float v = xs[cbase + c][q]; s = fmaf(v, v, s); }
    xsq_part[part][q] = s;
  }
  __syncthreads();
  if (tid < TQ)
    xsq[tid] = ((xsq_part[0][tid] + xsq_part[1][tid]) + xsq_part[2][tid]) + xsq_part[3][tid];
  __syncthreads();
  const int qt = tid & 15, kt = tid >> 4;
  float xsq_r[4];
#pragma unroll
  for (int i = 0; i < 4; ++i) xsq_r[i] = xsq[qt * 4 + i];
  float bd[4]; int bk[4];
#pragma unroll
  for (int i = 0; i < 4; ++i) { bd[i] = 3.4e38f; bk[i] = 0x7fffffff; }
  const int kbegin = blockIdx.y * R1_KCHUNK;
  for (int kt0 = kbegin; kt0 < kbegin + R1_KCHUNK; kt0 += TK) {
    __syncthreads();
    for (int idx = tid; idx < TK * (C_DIM / 4); idx += 256) {
      int kk = idx >> 6, c4 = idx & 63;
      float4 v = reinterpret_cast<const float4*>(cb + (size_t)(kt0 + kk) * C_DIM)[c4];
      es[kk][c4 * 4 + 0] = v.x; es[kk][c4 * 4 + 1] = v.y;
      es[kk][c4 * 4 + 2] = v.z; es[kk][c4 * 4 + 3] = v.w;
    }
    __syncthreads();
    float acc[4][4];
#pragma unroll
    for (int i = 0; i < 4; ++i)
#pragma unroll
      for (int j = 0; j < 4; ++j) acc[i][j] = 0.f;
    for (int c4 = 0; c4 < C_DIM; c4 += 4) {
      float4 xv0 = *reinterpret_cast<const float4*>(&xs[c4 + 0][qt * 4]);
      float4 xv1 = *reinterpret_cast<const float4*>(&xs[c4 + 1][qt * 4]);
      float4 xv2 = *reinterpret_cast<const float4*>(&xs[c4 + 2][qt * 4]);
      float4 xv3 = *reinterpret_cast<const float4*>(&xs[c4 + 3][qt * 4]);
      float xq0[4] = {xv0.x, xv0.y, xv0.z, xv0.w};
      float xq1[4] = {xv1.x, xv1.y, xv1.z, xv1.w};
      float xq2[4] = {xv2.x, xv2.y, xv2.z, xv2.w};
      float xq3[4] = {xv3.x, xv3.y, xv3.z, xv3.w};
      float4 ev[4];
#pragma unroll
      for (int j = 0; j < 4; ++j)
        ev[j] = *reinterpret_cast<const float4*>(&es[kt * 4 + j][c4]);
#pragma unroll
      for (int i = 0; i < 4; ++i) {
#pragma unroll
        for (int j = 0; j < 4; ++j) {
          float a = acc[i][j];
          a = fmaf(xq0[i], ev[j].x, a);
          a = fmaf(xq1[i], ev[j].y, a);
          a = fmaf(xq2[i], ev[j].z, a);
          a = fmaf(xq3[i], ev[j].w, a);
          acc[i][j] = a;
        }
      }
    }
#pragma unroll
    for (int j = 0; j < 4; ++j) {
      int k = kt0 + kt * 4 + j;
      float eq = esq[k];
#pragma unroll
      for (int i = 0; i < 4; ++i) {
        float t1 = xsq_r[i] + eq;
        float d = t1 - 2.0f * acc[i][j];
        if (d < bd[i]) { bd[i] = d; bk[i] = k; }
      }
    }
  }
#pragma unroll
  for (int i = 0; i < 4; ++i) {
    red_d[kt][qt * 4 + i] = bd[i];
    red_k[kt][qt * 4 + i] = bk[i];
  }
  __syncthreads();
  if (tid < TQ) {
    float d = red_d[0][tid]; int kb = red_k[0][tid];
    for (int t = 1; t < 16; ++t) {
      float dn = red_d[t][tid]; int kn = red_k[t][tid];
      if (dn < d || (dn == d && kn < kb)) { d = dn; kb = kn; }
    }
    int q = q0 + tid;
    ws_d[(size_t)q * R1_NCH + blockIdx.y] = d;
    ws_k[(size_t)q * R1_NCH + blockIdx.y] = kb;
  }
}

__global__ __launch_bounds__(256) void r1_final(
    const float* __restrict__ ws_d, const int* __restrict__ ws_k,
    int* __restrict__ out) {
  int n = blockIdx.x * blockDim.x + threadIdx.x;
  if (n >= N_Q) return;
  const float* dp = ws_d + (size_t)n * R1_NCH;
  const int* kp = ws_k + (size_t)n * R1_NCH;
  float d = dp[0]; int kb = kp[0];
#pragma unroll
  for (int j = 1; j < R1_NCH; ++j) {
    float dn = dp[j]; int kn = kp[j];
    if (dn < d || (dn == d && kn < kb)) { d = dn; kb = kn; }
  }
  out[n] = kb;
}

extern "C" void kernel_launch(void* const* d_in, const int* in_sizes, int n_in,
                              void* d_out, int out_size, void* d_ws,
                              size_t ws_size, hipStream_t stream) {
  const float* hidden = (const float*)d_in[0];
  const float* cb = (const float*)d_in[1];
  int* out = (int*)d_out;

  const size_t MB = 1024 * 1024;
  char* w = (char*)d_ws;
  unsigned short* xb = (unsigned short*)(w);                 // 4MB
  unsigned short* eb = (unsigned short*)(w + 4 * MB);        // 8MB
  float* xt = (float*)(w + 12 * MB);                         // 8MB
  float* xsq = (float*)(w + 20 * MB);                        // 32KB
  float* esq = (float*)(w + 20 * MB + 65536);                // 64KB
  u64* packed = (u64*)(w + 20 * MB + 196608);                // 64KB
  u64* packed2 = (u64*)(w + 20 * MB + 262144);               // 64KB
  float* mins_t = (float*)(w + 21 * MB);                     // 8MB [g][q]
  const size_t NEED = 29 * MB;  // proven available (R3/R5 passed)

  if (ws_size >= NEED) {
    vq_pre_x<<<dim3(N_Q / 256), dim3(256), 0, stream>>>(hidden, xt, xb, xsq,
                                                        packed, packed2);
    vq_pre_e<<<dim3(N_K / 256), dim3(256), 0, stream>>>(cb, eb, esq);
    vq_gemm<<<dim3((N_Q / BM) * (N_K / BN)), dim3(512), 0, stream>>>(
        xb, eb, xsq, esq, mins_t, packed);
    vq_rescore_s<<<dim3(NGRAN, RQS), dim3(256), 0, stream>>>(
        xt, cb, xsq, esq, mins_t, packed, packed2);
    vq_out<<<dim3(N_Q / 256), dim3(256), 0, stream>>>(packed2, out);
  } else {
    float* esq_f = (float*)d_ws;
    float* ws_d = (float*)((char*)d_ws + 65536);
    int* ws_k = (int*)((char*)d_ws + 65536 + N_Q * R1_NCH * 4);
    r1_esq<<<dim3(N_K / 256), dim3(256), 0, stream>>>(cb, esq_f);
    r1_main<<<dim3(N_Q / TQ, R1_NCH), dim3(256), 0, stream>>>(hidden, cb, esq_f, ws_d, ws_k);
    r1_final<<<dim3(N_Q / 256), dim3(256), 0, stream>>>(ws_d, ws_k, out);
  }
}

// Round 7
// 442.348 us; speedup vs baseline: 9.0609x; 1.3721x over previous
//
#include <hip/hip_runtime.h>

#define N_Q 8192
#define N_K 16384
#define C_DIM 256
#define BM 256
#define BN 256
#define BK 64
#define NGRAN 256   // 64-code granules
#define GRAN 64
// Rigorous worst-case |d_approx - d_np| <= 1.9e-4 (bf16 C-S term 1.3e-4 +
// epilogue reassociation 6e-5); flagging needs 2x = 3.8e-4. 4.5e-4 = 1.18x.
#define MARGIN 4.5e-4f
#define RQS 8            // query-splits per granule in rescore
#define RQB (N_Q / RQS)  // 1024 queries per rescore block

typedef __attribute__((ext_vector_type(8))) short short8;
typedef __attribute__((ext_vector_type(4))) float f32x4;
typedef __attribute__((ext_vector_type(4))) unsigned short ushort4_t;
typedef unsigned long long u64;

__device__ inline unsigned short f2bf(float f) {  // RNE fp32->bf16 (finite)
  unsigned u = __float_as_uint(f);
  return (unsigned short)((u + 0x7fffu + ((u >> 16) & 1u)) >> 16);
}

__device__ inline void gl_lds16(const void* g, void* l) {
  __builtin_amdgcn_global_load_lds(
      (const __attribute__((address_space(1))) unsigned int*)g,
      (__attribute__((address_space(3))) unsigned int*)l, 16, 0, 0);
}

// ===========================================================================
// pre_x v2: LDS-tile transpose (128 blocks x 64 queries). Coalesced hidden
// loads -> xs[c][q]; exact R1 xsq order (4 partials of 64 seq fmaf,
// ((p0+p1)+p2)+p3); coalesced xt/xb row writes; init packed/packed2.
// ===========================================================================
__global__ __launch_bounds__(256) void vq_pre_x(
    const float* __restrict__ hidden, float* __restrict__ xt,
    unsigned short* __restrict__ xb, float* __restrict__ xsq,
    u64* __restrict__ packed, u64* __restrict__ packed2) {
  __shared__ float xs[C_DIM][68];
  __shared__ float xsq_part[4][64];
  const int tile = blockIdx.x;       // 128 = 8 b x 16 hw-tiles
  const int b = tile >> 4;
  const int hw0 = (tile & 15) * 64;
  const int q0 = b * 1024 + hw0;
  const float* hb = hidden + (size_t)b * (C_DIM * 1024) + hw0;
  const int tid = threadIdx.x;

  for (int idx = tid; idx < C_DIM * 64; idx += 256) {
    int c = idx >> 6, q = idx & 63;
    xs[c][q] = hb[c * 1024 + q];     // coalesced over q
  }
  __syncthreads();

  {  // xsq, exact R1 order
    int q = tid & 63, part = tid >> 6, cb0 = part * 64;
    float s = 0.f;
    for (int c = 0; c < 64; ++c) { float v = xs[cb0 + c][q]; s = fmaf(v, v, s); }
    xsq_part[part][q] = s;
  }
  __syncthreads();
  if (tid < 64) {
    xsq[q0 + tid] = ((xsq_part[0][tid] + xsq_part[1][tid]) + xsq_part[2][tid]) +
                    xsq_part[3][tid];
    packed[q0 + tid] = ~0ull;
    packed2[q0 + tid] = ~0ull;
  }

  {  // xt + xb writes: thread t -> query tid>>2, 64-c segment (tid&3)*64
    int q = tid >> 2, c0 = (tid & 3) * 64;
    float* xo = xt + (size_t)(q0 + q) * C_DIM + c0;
    unsigned short* bo = xb + (size_t)(q0 + q) * C_DIM + c0;
    for (int i = 0; i < 64; i += 4) {
      float4 v = {xs[c0 + i][q], xs[c0 + i + 1][q], xs[c0 + i + 2][q],
                  xs[c0 + i + 3][q]};
      *reinterpret_cast<float4*>(xo + i) = v;
      ushort4_t bv = {f2bf(v.x), f2bf(v.y), f2bf(v.z), f2bf(v.w)};
      *reinterpret_cast<ushort4_t*>(bo + i) = bv;
    }
  }
}

// ===========================================================================
// pre_e v2: 256 blocks x 64 rows. Coalesced row staging -> LDS (stride 257 ->
// conflict-free chain reads); exact R1 esq chain per row; coalesced eb writes.
// ===========================================================================
__global__ __launch_bounds__(256) void vq_pre_e(
    const float* __restrict__ cb, unsigned short* __restrict__ eb,
    float* __restrict__ esq) {
  __shared__ float es[64][257];
  const int k0 = blockIdx.x * 64;
  const int tid = threadIdx.x;

  for (int idx = tid; idx < 64 * 64; idx += 256) {
    int kk = idx >> 6, c4 = idx & 63;   // coalesced float4 over c4
    float4 v = reinterpret_cast<const float4*>(cb + (size_t)(k0 + kk) * C_DIM)[c4];
    es[kk][c4 * 4 + 0] = v.x; es[kk][c4 * 4 + 1] = v.y;
    es[kk][c4 * 4 + 2] = v.z; es[kk][c4 * 4 + 3] = v.w;
  }
  __syncthreads();

  if (tid < 64) {  // exact sequential esq chain (R1 order)
    float s = 0.f;
    for (int c = 0; c < 256; ++c) { float v = es[tid][c]; s = fmaf(v, v, s); }
    esq[k0 + tid] = s;
  }

  {  // eb writes coalesced
    int r = tid >> 2, c0 = (tid & 3) * 64;
    unsigned short* bo = eb + (size_t)(k0 + r) * C_DIM + c0;
    for (int i = 0; i < 64; i += 4) {
      ushort4_t bv = {f2bf(es[r][c0 + i]), f2bf(es[r][c0 + i + 1]),
                      f2bf(es[r][c0 + i + 2]), f2bf(es[r][c0 + i + 3])};
      *reinterpret_cast<ushort4_t*>(bo + i) = bv;
    }
  }
}

// ===========================================================================
// Prefilter GEMM (R6-verified): 256x256 tile, 8 waves (2x4), BK=64 dbuf via
// global_load_lds, 16x16x32 bf16 MFMA. Wave = one 64-code granule.
// ===========================================================================
__global__ __launch_bounds__(512) void vq_gemm(
    const unsigned short* __restrict__ xb, const unsigned short* __restrict__ eb,
    const float* __restrict__ xsq, const float* __restrict__ esq,
    float* __restrict__ mins_t, u64* __restrict__ packed) {
  __shared__ __align__(16) unsigned short As[2][BM * BK];
  __shared__ __align__(16) unsigned short Bs[2][BN * BK];

  const int tid = threadIdx.x;
  const int wid = tid >> 6;
  const int lane = tid & 63;

  int bidx = blockIdx.x;
  int xcd = bidx & 7;
  int idx = bidx >> 3;
  int nb = xcd * 8 + (idx >> 5);
  int qb = idx & 31;
  const int q0 = qb * BM;
  const int n0 = nb * BN;

  const int wr = wid >> 2, wc = wid & 3;
  const int lrow = lane & 15;
  const int lkhi = lane >> 4;
  const int srow = lane >> 3;
  const int sseg = lane & 7;

  auto stage = [&](int kt, int bf) {
#pragma unroll
    for (int i = 0; i < 4; ++i) {
      int r0 = (wid * 4 + i) * 8;
      gl_lds16(xb + (size_t)(q0 + r0 + srow) * C_DIM + kt * BK + sseg * 8,
               (void*)((char*)&As[bf][0] + (size_t)r0 * BK * 2));
      gl_lds16(eb + (size_t)(n0 + r0 + srow) * C_DIM + kt * BK + sseg * 8,
               (void*)((char*)&Bs[bf][0] + (size_t)r0 * BK * 2));
    }
  };

  f32x4 acc[8][4];
#pragma unroll
  for (int i = 0; i < 8; ++i)
#pragma unroll
    for (int j = 0; j < 4; ++j) acc[i][j] = (f32x4){0.f, 0.f, 0.f, 0.f};

  stage(0, 0);
  asm volatile("s_waitcnt vmcnt(0)" ::: "memory");
  __syncthreads();

  for (int kt = 0; kt < C_DIM / BK; ++kt) {
    int bf = kt & 1;
    if (kt + 1 < C_DIM / BK) stage(kt + 1, bf ^ 1);
#pragma unroll
    for (int kk = 0; kk < 2; ++kk) {
      short8 a[8], b[4];
#pragma unroll
      for (int mi = 0; mi < 8; ++mi)
        a[mi] = *(const short8*)((const char*)&As[bf][0] +
                 (size_t)((wr * 128 + mi * 16 + lrow) * BK + kk * 32 + lkhi * 8) * 2);
#pragma unroll
      for (int ni = 0; ni < 4; ++ni)
        b[ni] = *(const short8*)((const char*)&Bs[bf][0] +
                 (size_t)((wc * 64 + ni * 16 + lrow) * BK + kk * 32 + lkhi * 8) * 2);
#pragma unroll
      for (int mi = 0; mi < 8; ++mi)
#pragma unroll
        for (int ni = 0; ni < 4; ++ni)
          acc[mi][ni] = __builtin_amdgcn_mfma_f32_16x16x32_bf16(
              a[mi], b[ni], acc[mi][ni], 0, 0, 0);
    }
    asm volatile("s_waitcnt vmcnt(0)" ::: "memory");
    __syncthreads();
  }

  float eqv[4];
#pragma unroll
  for (int ni = 0; ni < 4; ++ni) eqv[ni] = esq[n0 + wc * 64 + ni * 16 + lrow];
  const int g = nb * 4 + wc;
#pragma unroll
  for (int mi = 0; mi < 8; ++mi) {
#pragma unroll
    for (int j = 0; j < 4; ++j) {
      int row = q0 + wr * 128 + mi * 16 + lkhi * 4 + j;
      float xq = xsq[row];
      u64 bst = ~0ull;
#pragma unroll
      for (int ni = 0; ni < 4; ++ni) {
        float d = (xq + eqv[ni]) - 2.0f * acc[mi][ni][j];
        int k = n0 + wc * 64 + ni * 16 + lrow;
        u64 p = ((u64)__float_as_uint(d) << 32) | (unsigned)k;
        if (p < bst) bst = p;
      }
#pragma unroll
      for (int m = 1; m <= 8; m <<= 1) {
        u64 o = __shfl_xor(bst, m);
        if (o < bst) bst = o;
      }
      if (lrow == 0) {
        mins_t[(size_t)g * N_Q + row] = __uint_as_float((unsigned)(bst >> 32));
        atomicMin(&packed[row], bst);
      }
    }
  }
}

// ===========================================================================
// Rescore v3: NO code staging (e-rows read straight from L2/L3-resident cb),
// LDS = 4KB worklist only -> high occupancy/TLP. Block = (granule, 1024-query
// split); scan is lossless, lbuf bounded by scan range (cannot overflow).
// Each wave rescors 4 queries concurrently (4 independent EXACT R1 fmaf
// chains share each e-load). u64 atomicMin (first-index ties) -> packed2.
// ===========================================================================
__global__ __launch_bounds__(256) void vq_rescore_s(
    const float* __restrict__ xt, const float* __restrict__ cb,
    const float* __restrict__ xsq, const float* __restrict__ esq,
    const float* __restrict__ mins_t, const u64* __restrict__ packed,
    u64* __restrict__ packed2) {
  __shared__ int lcnt;
  __shared__ int lbuf[RQB];
  const int g = blockIdx.x;
  const int tid = threadIdx.x;
  if (tid == 0) lcnt = 0;
  __syncthreads();

  const int qbase = blockIdx.y * RQB;
  for (int c = 0; c < RQB; c += 256) {
    int q = qbase + c + tid;
    float thr = __uint_as_float((unsigned)(packed[q] >> 32)) + MARGIN;
    if (mins_t[(size_t)g * N_Q + q] <= thr) {
      int pos = atomicAdd(&lcnt, 1);
      lbuf[pos] = q;
    }
  }
  __syncthreads();

  const int n = lcnt;
  const int w = tid >> 6;
  const int l = tid & 63;
  const int k = g * GRAN + l;
  const float eq = esq[k];
  const float4* erow = (const float4*)(cb + (size_t)k * C_DIM);

  for (int i0 = w * 4; i0 < n; i0 += 16) {
    int qi[4];
#pragma unroll
    for (int j = 0; j < 4; ++j) {
      int ii = i0 + j;
      qi[j] = lbuf[ii < n ? ii : n - 1];  // clamp: dup work, same result
    }
    const float4* x0 = (const float4*)(xt + (size_t)qi[0] * C_DIM);
    const float4* x1 = (const float4*)(xt + (size_t)qi[1] * C_DIM);
    const float4* x2 = (const float4*)(xt + (size_t)qi[2] * C_DIM);
    const float4* x3 = (const float4*)(xt + (size_t)qi[3] * C_DIM);
    float a0 = 0.f, a1 = 0.f, a2 = 0.f, a3 = 0.f;
#pragma unroll 4
    for (int c4 = 0; c4 < 64; ++c4) {
      float4 e = erow[c4];
      float4 v0 = x0[c4];
      float4 v1 = x1[c4];
      float4 v2 = x2[c4];
      float4 v3 = x3[c4];
      a0 = fmaf(v0.x, e.x, a0); a0 = fmaf(v0.y, e.y, a0);
      a0 = fmaf(v0.z, e.z, a0); a0 = fmaf(v0.w, e.w, a0);
      a1 = fmaf(v1.x, e.x, a1); a1 = fmaf(v1.y, e.y, a1);
      a1 = fmaf(v1.z, e.z, a1); a1 = fmaf(v1.w, e.w, a1);
      a2 = fmaf(v2.x, e.x, a2); a2 = fmaf(v2.y, e.y, a2);
      a2 = fmaf(v2.z, e.z, a2); a2 = fmaf(v2.w, e.w, a2);
      a3 = fmaf(v3.x, e.x, a3); a3 = fmaf(v3.y, e.y, a3);
      a3 = fmaf(v3.z, e.z, a3); a3 = fmaf(v3.w, e.w, a3);
    }
    float dv[4] = {a0, a1, a2, a3};
#pragma unroll
    for (int j = 0; j < 4; ++j) {
      float d = (xsq[qi[j]] + eq) - 2.0f * dv[j];
      u64 p = ((u64)__float_as_uint(d) << 32) | (unsigned)k;
#pragma unroll
      for (int s = 1; s <= 32; s <<= 1) {
        u64 o = __shfl_xor(p, s);
        if (o < p) p = o;
      }
      if (l == 0) atomicMin(&packed2[qi[j]], p);
    }
  }
}

__global__ __launch_bounds__(256) void vq_out(const u64* __restrict__ packed2,
                                              int* __restrict__ out) {
  int n = blockIdx.x * 256 + threadIdx.x;
  if (n < N_Q) out[n] = (int)(unsigned)(packed2[n] & 0xffffffffull);
}

// ===========================================================================
// Fallback (R1, known-pass) if ws too small.
// ===========================================================================
#define TQ 64
#define TK 64
#define R1_NCH 8
#define R1_KCHUNK (N_K / R1_NCH)

__global__ __launch_bounds__(256) void r1_esq(const float* __restrict__ cb,
                                              float* __restrict__ esq) {
  int k = blockIdx.x * blockDim.x + threadIdx.x;
  if (k >= N_K) return;
  const float4* row = reinterpret_cast<const float4*>(cb + (size_t)k * C_DIM);
  float s = 0.f;
#pragma unroll 8
  for (int c4 = 0; c4 < C_DIM / 4; ++c4) {
    float4 v = row[c4];
    s = fmaf(v.x, v.x, s); s = fmaf(v.y, v.y, s);
    s = fmaf(v.z, v.z, s); s = fmaf(v.w, v.w, s);
  }
  esq[k] = s;
}

__global__ __launch_bounds__(256) void r1_main(
    const float* __restrict__ hidden, const float* __restrict__ cb,
    const float* __restrict__ esq, float* __restrict__ ws_d,
    int* __restrict__ ws_k) {
  __shared__ __align__(16) float xs[C_DIM][TQ + 4];
  __shared__ __align__(16) float es[TK][C_DIM + 4];
  __shared__ float xsq_part[4][TQ];
  __shared__ float xsq[TQ];
  __shared__ float red_d[16][TQ];
  __shared__ int red_k[16][TQ];
  const int tid = threadIdx.x;
  const int q0 = blockIdx.x * TQ;
  const int b = q0 >> 10;
  const int hw0 = q0 & 1023;
  const float* hb = hidden + (size_t)b * (C_DIM * 1024) + hw0;
  for (int idx = tid; idx < C_DIM * TQ; idx += 256) {
    int c = idx >> 6, q = idx & 63;
    xs[c][q] = hb[c * 1024 + q];
  }
  __syncthreads();
  {
    int q = tid & 63, part = tid >> 6, cbase = part * 64;
    float s = 0.f;
    for (int c = 0; c < 64; ++c) { float v = xs[cbase + c][q]; s = fmaf(v, v, s); }
    xsq_part[part][q] = s;
  }
  __syncthreads();
  if (tid < TQ)
    xsq[tid] = ((xsq_part[0][tid] + xsq_part[1][tid]) + xsq_part[2][tid]) + xsq_part[3][tid];
  __syncthreads();
  const int qt = tid & 15, kt = tid >> 4;
  float xsq_r[4];
#pragma unroll
  for (int i = 0; i < 4; ++i) xsq_r[i] = xsq[qt * 4 + i];
  float bd[4]; int bk[4];
#pragma unroll
  for (int i = 0; i < 4; ++i) { bd[i] = 3.4e38f; bk[i] = 0x7fffffff; }
  const int kbegin = blockIdx.y * R1_KCHUNK;
  for (int kt0 = kbegin; kt0 < kbegin + R1_KCHUNK; kt0 += TK) {
    __syncthreads();
    for (int idx = tid; idx < TK * (C_DIM / 4); idx += 256) {
      int kk = idx >> 6, c4 = idx & 63;
      float4 v = reinterpret_cast<const float4*>(cb + (size_t)(kt0 + kk) * C_DIM)[c4];
      es[kk][c4 * 4 + 0] = v.x; es[kk][c4 * 4 + 1] = v.y;
      es[kk][c4 * 4 + 2] = v.z; es[kk][c4 * 4 + 3] = v.w;
    }
    __syncthreads();
    float acc[4][4];
#pragma unroll
    for (int i = 0; i < 4; ++i)
#pragma unroll
      for (int j = 0; j < 4; ++j) acc[i][j] = 0.f;
    for (int c4 = 0; c4 < C_DIM; c4 += 4) {
      float4 xv0 = *reinterpret_cast<const float4*>(&xs[c4 + 0][qt * 4]);
      float4 xv1 = *reinterpret_cast<const float4*>(&xs[c4 + 1][qt * 4]);
      float4 xv2 = *reinterpret_cast<const float4*>(&xs[c4 + 2][qt * 4]);
      float4 xv3 = *reinterpret_cast<const float4*>(&xs[c4 + 3][qt * 4]);
      float xq0[4] = {xv0.x, xv0.y, xv0.z, xv0.w};
      float xq1[4] = {xv1.x, xv1.y, xv1.z, xv1.w};
      float xq2[4] = {xv2.x, xv2.y, xv2.z, xv2.w};
      float xq3[4] = {xv3.x, xv3.y, xv3.z, xv3.w};
      float4 ev[4];
#pragma unroll
      for (int j = 0; j < 4; ++j)
        ev[j] = *reinterpret_cast<const float4*>(&es[kt * 4 + j][c4]);
#pragma unroll
      for (int i = 0; i < 4; ++i) {
#pragma unroll
        for (int j = 0; j < 4; ++j) {
          float a = acc[i][j];
          a = fmaf(xq0[i], ev[j].x, a);
          a = fmaf(xq1[i], ev[j].y, a);
          a = fmaf(xq2[i], ev[j].z, a);
          a = fmaf(xq3[i], ev[j].w, a);
          acc[i][j] = a;
        }
      }
    }
#pragma unroll
    for (int j = 0; j < 4; ++j) {
      int k = kt0 + kt * 4 + j;
      float eq = esq[k];
#pragma unroll
      for (int i = 0; i < 4; ++i) {
        float t1 = xsq_r[i] + eq;
        float d = t1 - 2.0f * acc[i][j];
        if (d < bd[i]) { bd[i] = d; bk[i] = k; }
      }
    }
  }
#pragma unroll
  for (int i = 0; i < 4; ++i) {
    red_d[kt][qt * 4 + i] = bd[i];
    red_k[kt][qt * 4 + i] = bk[i];
  }
  __syncthreads();
  if (tid < TQ) {
    float d = red_d[0][tid]; int kb = red_k[0][tid];
    for (int t = 1; t < 16; ++t) {
      float dn = red_d[t][tid]; int kn = red_k[t][tid];
      if (dn < d || (dn == d && kn < kb)) { d = dn; kb = kn; }
    }
    int q = q0 + tid;
    ws_d[(size_t)q * R1_NCH + blockIdx.y] = d;
    ws_k[(size_t)q * R1_NCH + blockIdx.y] = kb;
  }
}

__global__ __launch_bounds__(256) void r1_final(
    const float* __restrict__ ws_d, const int* __restrict__ ws_k,
    int* __restrict__ out) {
  int n = blockIdx.x * blockDim.x + threadIdx.x;
  if (n >= N_Q) return;
  const float* dp = ws_d + (size_t)n * R1_NCH;
  const int* kp = ws_k + (size_t)n * R1_NCH;
  float d = dp[0]; int kb = kp[0];
#pragma unroll
  for (int j = 1; j < R1_NCH; ++j) {
    float dn = dp[j]; int kn = kp[j];
    if (dn < d || (dn == d && kn < kb)) { d = dn; kb = kn; }
  }
  out[n] = kb;
}

extern "C" void kernel_launch(void* const* d_in, const int* in_sizes, int n_in,
                              void* d_out, int out_size, void* d_ws,
                              size_t ws_size, hipStream_t stream) {
  const float* hidden = (const float*)d_in[0];
  const float* cb = (const float*)d_in[1];
  int* out = (int*)d_out;

  const size_t MB = 1024 * 1024;
  char* w = (char*)d_ws;
  unsigned short* xb = (unsigned short*)(w);                 // 4MB
  unsigned short* eb = (unsigned short*)(w + 4 * MB);        // 8MB
  float* xt = (float*)(w + 12 * MB);                         // 8MB
  float* xsq = (float*)(w + 20 * MB);                        // 32KB
  float* esq = (float*)(w + 20 * MB + 65536);                // 64KB
  u64* packed = (u64*)(w + 20 * MB + 196608);                // 64KB
  u64* packed2 = (u64*)(w + 20 * MB + 262144);               // 64KB
  float* mins_t = (float*)(w + 21 * MB);                     // 8MB [g][q]
  const size_t NEED = 29 * MB;  // proven available (R3/R5/R6 passed)

  if (ws_size >= NEED) {
    vq_pre_x<<<dim3(128), dim3(256), 0, stream>>>(hidden, xt, xb, xsq,
                                                  packed, packed2);
    vq_pre_e<<<dim3(N_K / 64), dim3(256), 0, stream>>>(cb, eb, esq);
    vq_gemm<<<dim3((N_Q / BM) * (N_K / BN)), dim3(512), 0, stream>>>(
        xb, eb, xsq, esq, mins_t, packed);
    vq_rescore_s<<<dim3(NGRAN, RQS), dim3(256), 0, stream>>>(
        xt, cb, xsq, esq, mins_t, packed, packed2);
    vq_out<<<dim3(N_Q / 256), dim3(256), 0, stream>>>(packed2, out);
  } else {
    float* esq_f = (float*)d_ws;
    float* ws_d = (float*)((char*)d_ws + 65536);
    int* ws_k = (int*)((char*)d_ws + 65536 + N_Q * R1_NCH * 4);
    r1_esq<<<dim3(N_K / 256), dim3(256), 0, stream>>>(cb, esq_f);
    r1_main<<<dim3(N_Q / TQ, R1_NCH), dim3(256), 0, stream>>>(hidden, cb, esq_f, ws_d, ws_k);
    r1_final<<<dim3(N_Q / 256), dim3(256), 0, stream>>>(ws_d, ws_k, out);
  }
}

// Round 8
// 426.509 us; speedup vs baseline: 9.3974x; 1.0371x over previous
//
#include <hip/hip_runtime.h>

#define N_Q 8192
#define N_K 16384
#define C_DIM 256
#define BM 256
#define BN 256
#define BK 64
#define NGRAN 256   // 64-code granules
#define GRAN 64
// Rigorous worst-case |d_approx - d_np| <= 1.9e-4 (bf16 C-S term 1.3e-4 +
// epilogue reassociation 6e-5); flagging needs 2x = 3.8e-4. 4.5e-4 = 1.18x.
#define MARGIN 4.5e-4f
#define RQS 8            // query-splits per granule in rescore
#define RQB (N_Q / RQS)  // 1024 queries per rescore block

typedef __attribute__((ext_vector_type(8))) short short8;
typedef __attribute__((ext_vector_type(4))) float f32x4;
typedef __attribute__((ext_vector_type(4))) unsigned short ushort4_t;
typedef unsigned long long u64;

__device__ inline unsigned short f2bf(float f) {  // RNE fp32->bf16 (finite)
  unsigned u = __float_as_uint(f);
  return (unsigned short)((u + 0x7fffu + ((u >> 16) & 1u)) >> 16);
}

__device__ inline void gl_lds16(const void* g, void* l) {
  __builtin_amdgcn_global_load_lds(
      (const __attribute__((address_space(1))) unsigned int*)g,
      (__attribute__((address_space(3))) unsigned int*)l, 16, 0, 0);
}

// ===========================================================================
// pre_x v2: LDS-tile transpose (128 blocks x 64 queries). Coalesced hidden
// loads -> xs[c][q]; exact R1 xsq order; coalesced xt/xb row writes.
// ===========================================================================
__global__ __launch_bounds__(256) void vq_pre_x(
    const float* __restrict__ hidden, float* __restrict__ xt,
    unsigned short* __restrict__ xb, float* __restrict__ xsq,
    u64* __restrict__ packed, u64* __restrict__ packed2) {
  __shared__ float xs[C_DIM][68];
  __shared__ float xsq_part[4][64];
  const int tile = blockIdx.x;       // 128 = 8 b x 16 hw-tiles
  const int b = tile >> 4;
  const int hw0 = (tile & 15) * 64;
  const int q0 = b * 1024 + hw0;
  const float* hb = hidden + (size_t)b * (C_DIM * 1024) + hw0;
  const int tid = threadIdx.x;

  for (int idx = tid; idx < C_DIM * 64; idx += 256) {
    int c = idx >> 6, q = idx & 63;
    xs[c][q] = hb[c * 1024 + q];     // coalesced over q
  }
  __syncthreads();

  {  // xsq, exact R1 order
    int q = tid & 63, part = tid >> 6, cb0 = part * 64;
    float s = 0.f;
    for (int c = 0; c < 64; ++c) { float v = xs[cb0 + c][q]; s = fmaf(v, v, s); }
    xsq_part[part][q] = s;
  }
  __syncthreads();
  if (tid < 64) {
    xsq[q0 + tid] = ((xsq_part[0][tid] + xsq_part[1][tid]) + xsq_part[2][tid]) +
                    xsq_part[3][tid];
    packed[q0 + tid] = ~0ull;
    packed2[q0 + tid] = ~0ull;
  }

  {  // xt + xb writes: thread t -> query tid>>2, 64-c segment (tid&3)*64
    int q = tid >> 2, c0 = (tid & 3) * 64;
    float* xo = xt + (size_t)(q0 + q) * C_DIM + c0;
    unsigned short* bo = xb + (size_t)(q0 + q) * C_DIM + c0;
    for (int i = 0; i < 64; i += 4) {
      float4 v = {xs[c0 + i][q], xs[c0 + i + 1][q], xs[c0 + i + 2][q],
                  xs[c0 + i + 3][q]};
      *reinterpret_cast<float4*>(xo + i) = v;
      ushort4_t bv = {f2bf(v.x), f2bf(v.y), f2bf(v.z), f2bf(v.w)};
      *reinterpret_cast<ushort4_t*>(bo + i) = bv;
    }
  }
}

// ===========================================================================
// pre_e v2: 256 blocks x 64 rows. Coalesced staging; exact R1 esq chain.
// ===========================================================================
__global__ __launch_bounds__(256) void vq_pre_e(
    const float* __restrict__ cb, unsigned short* __restrict__ eb,
    float* __restrict__ esq) {
  __shared__ float es[64][257];
  const int k0 = blockIdx.x * 64;
  const int tid = threadIdx.x;

  for (int idx = tid; idx < 64 * 64; idx += 256) {
    int kk = idx >> 6, c4 = idx & 63;
    float4 v = reinterpret_cast<const float4*>(cb + (size_t)(k0 + kk) * C_DIM)[c4];
    es[kk][c4 * 4 + 0] = v.x; es[kk][c4 * 4 + 1] = v.y;
    es[kk][c4 * 4 + 2] = v.z; es[kk][c4 * 4 + 3] = v.w;
  }
  __syncthreads();

  if (tid < 64) {  // exact sequential esq chain (R1 order)
    float s = 0.f;
    for (int c = 0; c < 256; ++c) { float v = es[tid][c]; s = fmaf(v, v, s); }
    esq[k0 + tid] = s;
  }

  {  // eb writes coalesced
    int r = tid >> 2, c0 = (tid & 3) * 64;
    unsigned short* bo = eb + (size_t)(k0 + r) * C_DIM + c0;
    for (int i = 0; i < 64; i += 4) {
      ushort4_t bv = {f2bf(es[r][c0 + i]), f2bf(es[r][c0 + i + 1]),
                      f2bf(es[r][c0 + i + 2]), f2bf(es[r][c0 + i + 3])};
      *reinterpret_cast<ushort4_t*>(bo + i) = bv;
    }
  }
}

// ===========================================================================
// Prefilter GEMM: 256x256 tile, 8 waves (2x4), BK=64 dbuf via global_load_lds,
// 16x16x32 bf16 MFMA. R8: XOR bank-swizzle, both-sides (rule 21) -- LDS dest
// linear; global SOURCE seg = (lane&7)^(lane>>3); READ seg = (kk*4+lkhi)^
// (row&7). LDS[row][t] = global[row][t^(row&7)]; reading t=s^(row&7) yields
// global[row][s]: bit-identical operands, kills the 16-way bank conflict.
// ===========================================================================
__global__ __launch_bounds__(512) void vq_gemm(
    const unsigned short* __restrict__ xb, const unsigned short* __restrict__ eb,
    const float* __restrict__ xsq, const float* __restrict__ esq,
    float* __restrict__ mins_t, u64* __restrict__ packed) {
  __shared__ __align__(16) unsigned short As[2][BM * BK];
  __shared__ __align__(16) unsigned short Bs[2][BN * BK];

  const int tid = threadIdx.x;
  const int wid = tid >> 6;
  const int lane = tid & 63;

  int bidx = blockIdx.x;
  int xcd = bidx & 7;
  int idx = bidx >> 3;
  int nb = xcd * 8 + (idx >> 5);
  int qb = idx & 31;
  const int q0 = qb * BM;
  const int n0 = nb * BN;

  const int wr = wid >> 2, wc = wid & 3;
  const int lrow = lane & 15;
  const int lkhi = lane >> 4;
  const int srow = lane >> 3;          // staging row within 8-row stripe
  const int sseg = (lane & 7) ^ srow;  // swizzled source segment (involution)

  auto stage = [&](int kt, int bf) {
#pragma unroll
    for (int i = 0; i < 4; ++i) {
      int r0 = (wid * 4 + i) * 8;  // multiple of 8 -> row&7 == srow
      gl_lds16(xb + (size_t)(q0 + r0 + srow) * C_DIM + kt * BK + sseg * 8,
               (void*)((char*)&As[bf][0] + (size_t)r0 * BK * 2));
      gl_lds16(eb + (size_t)(n0 + r0 + srow) * C_DIM + kt * BK + sseg * 8,
               (void*)((char*)&Bs[bf][0] + (size_t)r0 * BK * 2));
    }
  };

  f32x4 acc[8][4];
#pragma unroll
  for (int i = 0; i < 8; ++i)
#pragma unroll
    for (int j = 0; j < 4; ++j) acc[i][j] = (f32x4){0.f, 0.f, 0.f, 0.f};

  stage(0, 0);
  asm volatile("s_waitcnt vmcnt(0)" ::: "memory");
  __syncthreads();

  const int r7 = lrow & 7;  // row&7 for all frag rows (16-aligned bases)
  for (int kt = 0; kt < C_DIM / BK; ++kt) {
    int bf = kt & 1;
    if (kt + 1 < C_DIM / BK) stage(kt + 1, bf ^ 1);
#pragma unroll
    for (int kk = 0; kk < 2; ++kk) {
      const int segA = ((kk * 4 + lkhi) ^ r7) * 8;  // swizzled read (elems)
      short8 a[8], b[4];
#pragma unroll
      for (int mi = 0; mi < 8; ++mi)
        a[mi] = *(const short8*)((const char*)&As[bf][0] +
                 (size_t)((wr * 128 + mi * 16 + lrow) * BK + segA) * 2);
#pragma unroll
      for (int ni = 0; ni < 4; ++ni)
        b[ni] = *(const short8*)((const char*)&Bs[bf][0] +
                 (size_t)((wc * 64 + ni * 16 + lrow) * BK + segA) * 2);
#pragma unroll
      for (int mi = 0; mi < 8; ++mi)
#pragma unroll
        for (int ni = 0; ni < 4; ++ni)
          acc[mi][ni] = __builtin_amdgcn_mfma_f32_16x16x32_bf16(
              a[mi], b[ni], acc[mi][ni], 0, 0, 0);
    }
    asm volatile("s_waitcnt vmcnt(0)" ::: "memory");
    __syncthreads();
  }

  float eqv[4];
#pragma unroll
  for (int ni = 0; ni < 4; ++ni) eqv[ni] = esq[n0 + wc * 64 + ni * 16 + lrow];
  const int g = nb * 4 + wc;
#pragma unroll
  for (int mi = 0; mi < 8; ++mi) {
#pragma unroll
    for (int j = 0; j < 4; ++j) {
      int row = q0 + wr * 128 + mi * 16 + lkhi * 4 + j;
      float xq = xsq[row];
      u64 bst = ~0ull;
#pragma unroll
      for (int ni = 0; ni < 4; ++ni) {
        float d = (xq + eqv[ni]) - 2.0f * acc[mi][ni][j];
        int k = n0 + wc * 64 + ni * 16 + lrow;
        u64 p = ((u64)__float_as_uint(d) << 32) | (unsigned)k;
        if (p < bst) bst = p;
      }
#pragma unroll
      for (int m = 1; m <= 8; m <<= 1) {
        u64 o = __shfl_xor(bst, m);
        if (o < bst) bst = o;
      }
      if (lrow == 0) {
        mins_t[(size_t)g * N_Q + row] = __uint_as_float((unsigned)(bst >> 32));
        atomicMin(&packed[row], bst);
      }
    }
  }
}

// ===========================================================================
// Rescore v3 (R7-verified): no staging, 4KB LDS worklist, high occupancy,
// 4 exact R1 chains per wave sharing each e-load. atomicMin -> packed2.
// ===========================================================================
__global__ __launch_bounds__(256) void vq_rescore_s(
    const float* __restrict__ xt, const float* __restrict__ cb,
    const float* __restrict__ xsq, const float* __restrict__ esq,
    const float* __restrict__ mins_t, const u64* __restrict__ packed,
    u64* __restrict__ packed2) {
  __shared__ int lcnt;
  __shared__ int lbuf[RQB];
  const int g = blockIdx.x;
  const int tid = threadIdx.x;
  if (tid == 0) lcnt = 0;
  __syncthreads();

  const int qbase = blockIdx.y * RQB;
  for (int c = 0; c < RQB; c += 256) {
    int q = qbase + c + tid;
    float thr = __uint_as_float((unsigned)(packed[q] >> 32)) + MARGIN;
    if (mins_t[(size_t)g * N_Q + q] <= thr) {
      int pos = atomicAdd(&lcnt, 1);
      lbuf[pos] = q;
    }
  }
  __syncthreads();

  const int n = lcnt;
  const int w = tid >> 6;
  const int l = tid & 63;
  const int k = g * GRAN + l;
  const float eq = esq[k];
  const float4* erow = (const float4*)(cb + (size_t)k * C_DIM);

  for (int i0 = w * 4; i0 < n; i0 += 16) {
    int qi[4];
#pragma unroll
    for (int j = 0; j < 4; ++j) {
      int ii = i0 + j;
      qi[j] = lbuf[ii < n ? ii : n - 1];  // clamp: dup work, same result
    }
    const float4* x0 = (const float4*)(xt + (size_t)qi[0] * C_DIM);
    const float4* x1 = (const float4*)(xt + (size_t)qi[1] * C_DIM);
    const float4* x2 = (const float4*)(xt + (size_t)qi[2] * C_DIM);
    const float4* x3 = (const float4*)(xt + (size_t)qi[3] * C_DIM);
    float a0 = 0.f, a1 = 0.f, a2 = 0.f, a3 = 0.f;
#pragma unroll 4
    for (int c4 = 0; c4 < 64; ++c4) {
      float4 e = erow[c4];
      float4 v0 = x0[c4];
      float4 v1 = x1[c4];
      float4 v2 = x2[c4];
      float4 v3 = x3[c4];
      a0 = fmaf(v0.x, e.x, a0); a0 = fmaf(v0.y, e.y, a0);
      a0 = fmaf(v0.z, e.z, a0); a0 = fmaf(v0.w, e.w, a0);
      a1 = fmaf(v1.x, e.x, a1); a1 = fmaf(v1.y, e.y, a1);
      a1 = fmaf(v1.z, e.z, a1); a1 = fmaf(v1.w, e.w, a1);
      a2 = fmaf(v2.x, e.x, a2); a2 = fmaf(v2.y, e.y, a2);
      a2 = fmaf(v2.z, e.z, a2); a2 = fmaf(v2.w, e.w, a2);
      a3 = fmaf(v3.x, e.x, a3); a3 = fmaf(v3.y, e.y, a3);
      a3 = fmaf(v3.z, e.z, a3); a3 = fmaf(v3.w, e.w, a3);
    }
    float dv[4] = {a0, a1, a2, a3};
#pragma unroll
    for (int j = 0; j < 4; ++j) {
      float d = (xsq[qi[j]] + eq) - 2.0f * dv[j];
      u64 p = ((u64)__float_as_uint(d) << 32) | (unsigned)k;
#pragma unroll
      for (int s = 1; s <= 32; s <<= 1) {
        u64 o = __shfl_xor(p, s);
        if (o < p) p = o;
      }
      if (l == 0) atomicMin(&packed2[qi[j]], p);
    }
  }
}

__global__ __launch_bounds__(256) void vq_out(const u64* __restrict__ packed2,
                                              int* __restrict__ out) {
  int n = blockIdx.x * 256 + threadIdx.x;
  if (n < N_Q) out[n] = (int)(unsigned)(packed2[n] & 0xffffffffull);
}

// ===========================================================================
// Fallback (R1, known-pass) if ws too small.
// ===========================================================================
#define TQ 64
#define TK 64
#define R1_NCH 8
#define R1_KCHUNK (N_K / R1_NCH)

__global__ __launch_bounds__(256) void r1_esq(const float* __restrict__ cb,
                                              float* __restrict__ esq) {
  int k = blockIdx.x * blockDim.x + threadIdx.x;
  if (k >= N_K) return;
  const float4* row = reinterpret_cast<const float4*>(cb + (size_t)k * C_DIM);
  float s = 0.f;
#pragma unroll 8
  for (int c4 = 0; c4 < C_DIM / 4; ++c4) {
    float4 v = row[c4];
    s = fmaf(v.x, v.x, s); s = fmaf(v.y, v.y, s);
    s = fmaf(v.z, v.z, s); s = fmaf(v.w, v.w, s);
  }
  esq[k] = s;
}

__global__ __launch_bounds__(256) void r1_main(
    const float* __restrict__ hidden, const float* __restrict__ cb,
    const float* __restrict__ esq, float* __restrict__ ws_d,
    int* __restrict__ ws_k) {
  __shared__ __align__(16) float xs[C_DIM][TQ + 4];
  __shared__ __align__(16) float es[TK][C_DIM + 4];
  __shared__ float xsq_part[4][TQ];
  __shared__ float xsq[TQ];
  __shared__ float red_d[16][TQ];
  __shared__ int red_k[16][TQ];
  const int tid = threadIdx.x;
  const int q0 = blockIdx.x * TQ;
  const int b = q0 >> 10;
  const int hw0 = q0 & 1023;
  const float* hb = hidden + (size_t)b * (C_DIM * 1024) + hw0;
  for (int idx = tid; idx < C_DIM * TQ; idx += 256) {
    int c = idx >> 6, q = idx & 63;
    xs[c][q] = hb[c * 1024 + q];
  }
  __syncthreads();
  {
    int q = tid & 63, part = tid >> 6, cbase = part * 64;
    float s = 0.f;
    for (int c = 0; c < 64; ++c) { float v = xs[cbase + c][q]; s = fmaf(v, v, s); }
    xsq_part[part][q] = s;
  }
  __syncthreads();
  if (tid < TQ)
    xsq[tid] = ((xsq_part[0][tid] + xsq_part[1][tid]) + xsq_part[2][tid]) + xsq_part[3][tid];
  __syncthreads();
  const int qt = tid & 15, kt = tid >> 4;
  float xsq_r[4];
#pragma unroll
  for (int i = 0; i < 4; ++i) xsq_r[i] = xsq[qt * 4 + i];
  float bd[4]; int bk[4];
#pragma unroll
  for (int i = 0; i < 4; ++i) { bd[i] = 3.4e38f; bk[i] = 0x7fffffff; }
  const int kbegin = blockIdx.y * R1_KCHUNK;
  for (int kt0 = kbegin; kt0 < kbegin + R1_KCHUNK; kt0 += TK) {
    __syncthreads();
    for (int idx = tid; idx < TK * (C_DIM / 4); idx += 256) {
      int kk = idx >> 6, c4 = idx & 63;
      float4 v = reinterpret_cast<const float4*>(cb + (size_t)(kt0 + kk) * C_DIM)[c4];
      es[kk][c4 * 4 + 0] = v.x; es[kk][c4 * 4 + 1] = v.y;
      es[kk][c4 * 4 + 2] = v.z; es[kk][c4 * 4 + 3] = v.w;
    }
    __syncthreads();
    float acc[4][4];
#pragma unroll
    for (int i = 0; i < 4; ++i)
#pragma unroll
      for (int j = 0; j < 4; ++j) acc[i][j] = 0.f;
    for (int c4 = 0; c4 < C_DIM; c4 += 4) {
      float4 xv0 = *reinterpret_cast<const float4*>(&xs[c4 + 0][qt * 4]);
      float4 xv1 = *reinterpret_cast<const float4*>(&xs[c4 + 1][qt * 4]);
      float4 xv2 = *reinterpret_cast<const float4*>(&xs[c4 + 2][qt * 4]);
      float4 xv3 = *reinterpret_cast<const float4*>(&xs[c4 + 3][qt * 4]);
      float xq0[4] = {xv0.x, xv0.y, xv0.z, xv0.w};
      float xq1[4] = {xv1.x, xv1.y, xv1.z, xv1.w};
      float xq2[4] = {xv2.x, xv2.y, xv2.z, xv2.w};
      float xq3[4] = {xv3.x, xv3.y, xv3.z, xv3.w};
      float4 ev[4];
#pragma unroll
      for (int j = 0; j < 4; ++j)
        ev[j] = *reinterpret_cast<const float4*>(&es[kt * 4 + j][c4]);
#pragma unroll
      for (int i = 0; i < 4; ++i) {
#pragma unroll
        for (int j = 0; j < 4; ++j) {
          float a = acc[i][j];
          a = fmaf(xq0[i], ev[j].x, a);
          a = fmaf(xq1[i], ev[j].y, a);
          a = fmaf(xq2[i], ev[j].z, a);
          a = fmaf(xq3[i], ev[j].w, a);
          acc[i][j] = a;
        }
      }
    }
#pragma unroll
    for (int j = 0; j < 4; ++j) {
      int k = kt0 + kt * 4 + j;
      float eq = esq[k];
#pragma unroll
      for (int i = 0; i < 4; ++i) {
        float t1 = xsq_r[i] + eq;
        float d = t1 - 2.0f * acc[i][j];
        if (d < bd[i]) { bd[i] = d; bk[i] = k; }
      }
    }
  }
#pragma unroll
  for (int i = 0; i < 4; ++i) {
    red_d[kt][qt * 4 + i] = bd[i];
    red_k[kt][qt * 4 + i] = bk[i];
  }
  __syncthreads();
  if (tid < TQ) {
    float d = red_d[0][tid]; int kb = red_k[0][tid];
    for (int t = 1; t < 16; ++t) {
      float dn = red_d[t][tid]; int kn = red_k[t][tid];
      if (dn < d || (dn == d && kn < kb)) { d = dn; kb = kn; }
    }
    int q = q0 + tid;
    ws_d[(size_t)q * R1_NCH + blockIdx.y] = d;
    ws_k[(size_t)q * R1_NCH + blockIdx.y] = kb;
  }
}

__global__ __launch_bounds__(256) void r1_final(
    const float* __restrict__ ws_d, const int* __restrict__ ws_k,
    int* __restrict__ out) {
  int n = blockIdx.x * blockDim.x + threadIdx.x;
  if (n >= N_Q) return;
  const float* dp = ws_d + (size_t)n * R1_NCH;
  const int* kp = ws_k + (size_t)n * R1_NCH;
  float d = dp[0]; int kb = kp[0];
#pragma unroll
  for (int j = 1; j < R1_NCH; ++j) {
    float dn = dp[j]; int kn = kp[j];
    if (dn < d || (dn == d && kn < kb)) { d = dn; kb = kn; }
  }
  out[n] = kb;
}

extern "C" void kernel_launch(void* const* d_in, const int* in_sizes, int n_in,
                              void* d_out, int out_size, void* d_ws,
                              size_t ws_size, hipStream_t stream) {
  const float* hidden = (const float*)d_in[0];
  const float* cb = (const float*)d_in[1];
  int* out = (int*)d_out;

  const size_t MB = 1024 * 1024;
  char* w = (char*)d_ws;
  unsigned short* xb = (unsigned short*)(w);                 // 4MB
  unsigned short* eb = (unsigned short*)(w + 4 * MB);        // 8MB
  float* xt = (float*)(w + 12 * MB);                         // 8MB
  float* xsq = (float*)(w + 20 * MB);                        // 32KB
  float* esq = (float*)(w + 20 * MB + 65536);                // 64KB
  u64* packed = (u64*)(w + 20 * MB + 196608);                // 64KB
  u64* packed2 = (u64*)(w + 20 * MB + 262144);               // 64KB
  float* mins_t = (float*)(w + 21 * MB);                     // 8MB [g][q]
  const size_t NEED = 29 * MB;  // proven available

  if (ws_size >= NEED) {
    vq_pre_x<<<dim3(128), dim3(256), 0, stream>>>(hidden, xt, xb, xsq,
                                                  packed, packed2);
    vq_pre_e<<<dim3(N_K / 64), dim3(256), 0, stream>>>(cb, eb, esq);
    vq_gemm<<<dim3((N_Q / BM) * (N_K / BN)), dim3(512), 0, stream>>>(
        xb, eb, xsq, esq, mins_t, packed);
    vq_rescore_s<<<dim3(NGRAN, RQS), dim3(256), 0, stream>>>(
        xt, cb, xsq, esq, mins_t, packed, packed2);
    vq_out<<<dim3(N_Q / 256), dim3(256), 0, stream>>>(packed2, out);
  } else {
    float* esq_f = (float*)d_ws;
    float* ws_d = (float*)((char*)d_ws + 65536);
    int* ws_k = (int*)((char*)d_ws + 65536 + N_Q * R1_NCH * 4);
    r1_esq<<<dim3(N_K / 256), dim3(256), 0, stream>>>(cb, esq_f);
    r1_main<<<dim3(N_Q / TQ, R1_NCH), dim3(256), 0, stream>>>(hidden, cb, esq_f, ws_d, ws_k);
    r1_final<<<dim3(N_Q / 256), dim3(256), 0, stream>>>(ws_d, ws_k, out);
  }
}

// Round 9
// 324.146 us; speedup vs baseline: 12.3650x; 1.3158x over previous
//
#include <hip/hip_runtime.h>

#define N_Q 8192
#define N_K 16384
#define C_DIM 256
#define BM 256
#define BN 256
#define BK 64
#define NGRAN 256   // 64-code granules
#define GRAN 64
// Rigorous worst-case |d_approx - d_np| <= 1.9e-4; flagging needs 2x = 3.8e-4.
#define MARGIN 4.5e-4f
#define RQS 16           // query-splits per granule in rescore
#define RQB (N_Q / RQS)  // 512 queries per rescore block

typedef __attribute__((ext_vector_type(8))) short short8;
typedef __attribute__((ext_vector_type(4))) float f32x4;
typedef __attribute__((ext_vector_type(4))) unsigned short ushort4_t;
typedef unsigned long long u64;

__device__ inline unsigned short f2bf(float f) {  // RNE fp32->bf16 (finite)
  unsigned u = __float_as_uint(f);
  return (unsigned short)((u + 0x7fffu + ((u >> 16) & 1u)) >> 16);
}

__device__ inline void gl_lds16(const void* g, void* l) {
  __builtin_amdgcn_global_load_lds(
      (const __attribute__((address_space(1))) unsigned int*)g,
      (__attribute__((address_space(3))) unsigned int*)l, 16, 0, 0);
}

// ===========================================================================
// pre_x: LDS-tile transpose; exact R1 xsq order; init packed2.
// ===========================================================================
__global__ __launch_bounds__(256) void vq_pre_x(
    const float* __restrict__ hidden, float* __restrict__ xt,
    unsigned short* __restrict__ xb, float* __restrict__ xsq,
    u64* __restrict__ packed2) {
  __shared__ float xs[C_DIM][68];
  __shared__ float xsq_part[4][64];
  const int tile = blockIdx.x;       // 128 = 8 b x 16 hw-tiles
  const int b = tile >> 4;
  const int hw0 = (tile & 15) * 64;
  const int q0 = b * 1024 + hw0;
  const float* hb = hidden + (size_t)b * (C_DIM * 1024) + hw0;
  const int tid = threadIdx.x;

  for (int idx = tid; idx < C_DIM * 64; idx += 256) {
    int c = idx >> 6, q = idx & 63;
    xs[c][q] = hb[c * 1024 + q];     // coalesced over q
  }
  __syncthreads();

  {  // xsq, exact R1 order
    int q = tid & 63, part = tid >> 6, cb0 = part * 64;
    float s = 0.f;
    for (int c = 0; c < 64; ++c) { float v = xs[cb0 + c][q]; s = fmaf(v, v, s); }
    xsq_part[part][q] = s;
  }
  __syncthreads();
  if (tid < 64) {
    xsq[q0 + tid] = ((xsq_part[0][tid] + xsq_part[1][tid]) + xsq_part[2][tid]) +
                    xsq_part[3][tid];
    packed2[q0 + tid] = ~0ull;
  }

  {  // xt + xb row writes
    int q = tid >> 2, c0 = (tid & 3) * 64;
    float* xo = xt + (size_t)(q0 + q) * C_DIM + c0;
    unsigned short* bo = xb + (size_t)(q0 + q) * C_DIM + c0;
    for (int i = 0; i < 64; i += 4) {
      float4 v = {xs[c0 + i][q], xs[c0 + i + 1][q], xs[c0 + i + 2][q],
                  xs[c0 + i + 3][q]};
      *reinterpret_cast<float4*>(xo + i) = v;
      ushort4_t bv = {f2bf(v.x), f2bf(v.y), f2bf(v.z), f2bf(v.w)};
      *reinterpret_cast<ushort4_t*>(bo + i) = bv;
    }
  }
}

// ===========================================================================
// pre_e: coalesced staging; exact R1 esq; eb bf16; optional transposed fp32
// codebook ct[c][k] (for coalesced rescore gathers). ct[c][k] == cb[k][c]
// bit-exactly.
// ===========================================================================
__global__ __launch_bounds__(256) void vq_pre_e(
    const float* __restrict__ cb, unsigned short* __restrict__ eb,
    float* __restrict__ esq, float* __restrict__ ct) {
  __shared__ float es[64][257];
  const int k0 = blockIdx.x * 64;
  const int tid = threadIdx.x;

  for (int idx = tid; idx < 64 * 64; idx += 256) {
    int kk = idx >> 6, c4 = idx & 63;
    float4 v = reinterpret_cast<const float4*>(cb + (size_t)(k0 + kk) * C_DIM)[c4];
    es[kk][c4 * 4 + 0] = v.x; es[kk][c4 * 4 + 1] = v.y;
    es[kk][c4 * 4 + 2] = v.z; es[kk][c4 * 4 + 3] = v.w;
  }
  __syncthreads();

  if (tid < 64) {  // exact sequential esq chain (R1 order)
    float s = 0.f;
    for (int c = 0; c < 256; ++c) { float v = es[tid][c]; s = fmaf(v, v, s); }
    esq[k0 + tid] = s;
  }

  {  // eb writes coalesced
    int r = tid >> 2, c0 = (tid & 3) * 64;
    unsigned short* bo = eb + (size_t)(k0 + r) * C_DIM + c0;
    for (int i = 0; i < 64; i += 4) {
      ushort4_t bv = {f2bf(es[r][c0 + i]), f2bf(es[r][c0 + i + 1]),
                      f2bf(es[r][c0 + i + 2]), f2bf(es[r][c0 + i + 3])};
      *reinterpret_cast<ushort4_t*>(bo + i) = bv;
    }
  }

  if (ct) {  // transposed write: lanes = rows -> coalesced 256B stores
    const int l = tid & 63, w4 = tid >> 6;
    for (int c = w4; c < C_DIM; c += 4) {
      ct[(size_t)c * N_K + k0 + l] = es[l][c];  // LDS col read: (l+c)%32, 2-way
    }
  }
}

// ===========================================================================
// Prefilter GEMM (R8-verified swizzle, conflicts=0). R9: NO atomics --
// epilogue writes mins_t only; global threshold moved to vq_thr.
// ===========================================================================
__global__ __launch_bounds__(512) void vq_gemm(
    const unsigned short* __restrict__ xb, const unsigned short* __restrict__ eb,
    const float* __restrict__ xsq, const float* __restrict__ esq,
    float* __restrict__ mins_t) {
  __shared__ __align__(16) unsigned short As[2][BM * BK];
  __shared__ __align__(16) unsigned short Bs[2][BN * BK];

  const int tid = threadIdx.x;
  const int wid = tid >> 6;
  const int lane = tid & 63;

  int bidx = blockIdx.x;
  int xcd = bidx & 7;
  int idx = bidx >> 3;
  int nb = xcd * 8 + (idx >> 5);
  int qb = idx & 31;
  const int q0 = qb * BM;
  const int n0 = nb * BN;

  const int wr = wid >> 2, wc = wid & 3;
  const int lrow = lane & 15;
  const int lkhi = lane >> 4;
  const int srow = lane >> 3;          // staging row within 8-row stripe
  const int sseg = (lane & 7) ^ srow;  // swizzled source segment (involution)

  auto stage = [&](int kt, int bf) {
#pragma unroll
    for (int i = 0; i < 4; ++i) {
      int r0 = (wid * 4 + i) * 8;  // multiple of 8 -> row&7 == srow
      gl_lds16(xb + (size_t)(q0 + r0 + srow) * C_DIM + kt * BK + sseg * 8,
               (void*)((char*)&As[bf][0] + (size_t)r0 * BK * 2));
      gl_lds16(eb + (size_t)(n0 + r0 + srow) * C_DIM + kt * BK + sseg * 8,
               (void*)((char*)&Bs[bf][0] + (size_t)r0 * BK * 2));
    }
  };

  f32x4 acc[8][4];
#pragma unroll
  for (int i = 0; i < 8; ++i)
#pragma unroll
    for (int j = 0; j < 4; ++j) acc[i][j] = (f32x4){0.f, 0.f, 0.f, 0.f};

  stage(0, 0);
  asm volatile("s_waitcnt vmcnt(0)" ::: "memory");
  __syncthreads();

  const int r7 = lrow & 7;
  for (int kt = 0; kt < C_DIM / BK; ++kt) {
    int bf = kt & 1;
    if (kt + 1 < C_DIM / BK) stage(kt + 1, bf ^ 1);
#pragma unroll
    for (int kk = 0; kk < 2; ++kk) {
      const int segA = ((kk * 4 + lkhi) ^ r7) * 8;  // swizzled read (elems)
      short8 a[8], b[4];
#pragma unroll
      for (int mi = 0; mi < 8; ++mi)
        a[mi] = *(const short8*)((const char*)&As[bf][0] +
                 (size_t)((wr * 128 + mi * 16 + lrow) * BK + segA) * 2);
#pragma unroll
      for (int ni = 0; ni < 4; ++ni)
        b[ni] = *(const short8*)((const char*)&Bs[bf][0] +
                 (size_t)((wc * 64 + ni * 16 + lrow) * BK + segA) * 2);
#pragma unroll
      for (int mi = 0; mi < 8; ++mi)
#pragma unroll
        for (int ni = 0; ni < 4; ++ni)
          acc[mi][ni] = __builtin_amdgcn_mfma_f32_16x16x32_bf16(
              a[mi], b[ni], acc[mi][ni], 0, 0, 0);
    }
    asm volatile("s_waitcnt vmcnt(0)" ::: "memory");
    __syncthreads();
  }

  float eqv[4];
#pragma unroll
  for (int ni = 0; ni < 4; ++ni) eqv[ni] = esq[n0 + wc * 64 + ni * 16 + lrow];
  const int g = nb * 4 + wc;
#pragma unroll
  for (int mi = 0; mi < 8; ++mi) {
#pragma unroll
    for (int j = 0; j < 4; ++j) {
      int row = q0 + wr * 128 + mi * 16 + lkhi * 4 + j;
      float xq = xsq[row];
      u64 bst = ~0ull;
#pragma unroll
      for (int ni = 0; ni < 4; ++ni) {
        float d = (xq + eqv[ni]) - 2.0f * acc[mi][ni][j];
        int k = n0 + wc * 64 + ni * 16 + lrow;
        u64 p = ((u64)__float_as_uint(d) << 32) | (unsigned)k;
        if (p < bst) bst = p;
      }
#pragma unroll
      for (int m = 1; m <= 8; m <<= 1) {
        u64 o = __shfl_xor(bst, m);
        if (o < bst) bst = o;
      }
      if (lrow == 0)
        mins_t[(size_t)g * N_Q + row] = __uint_as_float((unsigned)(bst >> 32));
    }
  }
}

// ===========================================================================
// thr[q] = min_g mins_t[g][q] + MARGIN. Coalesced column-min (consecutive
// threads -> consecutive q). Replaces the gemm's 2M packed atomics.
// ===========================================================================
__global__ __launch_bounds__(256) void vq_thr(const float* __restrict__ mins_t,
                                              float* __restrict__ thr) {
  int q = blockIdx.x * 256 + threadIdx.x;
  float m = 3.4e38f;
  for (int g = 0; g < NGRAN; ++g) m = fminf(m, mins_t[(size_t)g * N_Q + q]);
  thr[q] = m + MARGIN;
}

// ===========================================================================
// Rescore v4: flag-scan (lossless, list bounded by scan range), then exact
// R1 fmaf chains, 4 queries per wave. e read either from ct (transposed,
// coalesced: lane l -> ct[c][g*64+l]) or cb-direct (R8 fallback). Values and
// chain order are identical in both paths. u64 atomicMin -> packed2.
// ===========================================================================
__global__ __launch_bounds__(256) void vq_rescore_s(
    const float* __restrict__ xt, const float* __restrict__ cb,
    const float* __restrict__ ct, const float* __restrict__ xsq,
    const float* __restrict__ esq, const float* __restrict__ mins_t,
    const float* __restrict__ thr, u64* __restrict__ packed2) {
  __shared__ int lcnt;
  __shared__ int lbuf[RQB];
  const int g = blockIdx.x;
  const int tid = threadIdx.x;
  if (tid == 0) lcnt = 0;
  __syncthreads();

  const int qbase = blockIdx.y * RQB;
  for (int c = 0; c < RQB; c += 256) {
    int q = qbase + c + tid;
    if (mins_t[(size_t)g * N_Q + q] <= thr[q]) {
      int pos = atomicAdd(&lcnt, 1);
      lbuf[pos] = q;
    }
  }
  __syncthreads();

  const int n = lcnt;
  const int w = tid >> 6;
  const int l = tid & 63;
  const int k = g * GRAN + l;
  const float eq = esq[k];

  for (int i0 = w * 4; i0 < n; i0 += 16) {
    int qi[4];
#pragma unroll
    for (int j = 0; j < 4; ++j) {
      int ii = i0 + j;
      qi[j] = lbuf[ii < n ? ii : n - 1];  // clamp: dup work, same result
    }
    const float4* x0 = (const float4*)(xt + (size_t)qi[0] * C_DIM);
    const float4* x1 = (const float4*)(xt + (size_t)qi[1] * C_DIM);
    const float4* x2 = (const float4*)(xt + (size_t)qi[2] * C_DIM);
    const float4* x3 = (const float4*)(xt + (size_t)qi[3] * C_DIM);
    float a0 = 0.f, a1 = 0.f, a2 = 0.f, a3 = 0.f;
    if (ct) {
      const float* ec = ct + k;  // ct[c][k] = ec[c*N_K]
#pragma unroll 4
      for (int c4 = 0; c4 < 64; ++c4) {
        float e0 = ec[(size_t)(c4 * 4 + 0) * N_K];  // coalesced over lanes
        float e1 = ec[(size_t)(c4 * 4 + 1) * N_K];
        float e2 = ec[(size_t)(c4 * 4 + 2) * N_K];
        float e3 = ec[(size_t)(c4 * 4 + 3) * N_K];
        float4 v0 = x0[c4], v1 = x1[c4], v2 = x2[c4], v3 = x3[c4];
        a0 = fmaf(v0.x, e0, a0); a0 = fmaf(v0.y, e1, a0);
        a0 = fmaf(v0.z, e2, a0); a0 = fmaf(v0.w, e3, a0);
        a1 = fmaf(v1.x, e0, a1); a1 = fmaf(v1.y, e1, a1);
        a1 = fmaf(v1.z, e2, a1); a1 = fmaf(v1.w, e3, a1);
        a2 = fmaf(v2.x, e0, a2); a2 = fmaf(v2.y, e1, a2);
        a2 = fmaf(v2.z, e2, a2); a2 = fmaf(v2.w, e3, a2);
        a3 = fmaf(v3.x, e0, a3); a3 = fmaf(v3.y, e1, a3);
        a3 = fmaf(v3.z, e2, a3); a3 = fmaf(v3.w, e3, a3);
      }
    } else {
      const float4* erow = (const float4*)(cb + (size_t)k * C_DIM);
#pragma unroll 4
      for (int c4 = 0; c4 < 64; ++c4) {
        float4 e = erow[c4];
        float4 v0 = x0[c4], v1 = x1[c4], v2 = x2[c4], v3 = x3[c4];
        a0 = fmaf(v0.x, e.x, a0); a0 = fmaf(v0.y, e.y, a0);
        a0 = fmaf(v0.z, e.z, a0); a0 = fmaf(v0.w, e.w, a0);
        a1 = fmaf(v1.x, e.x, a1); a1 = fmaf(v1.y, e.y, a1);
        a1 = fmaf(v1.z, e.z, a1); a1 = fmaf(v1.w, e.w, a1);
        a2 = fmaf(v2.x, e.x, a2); a2 = fmaf(v2.y, e.y, a2);
        a2 = fmaf(v2.z, e.z, a2); a2 = fmaf(v2.w, e.w, a2);
        a3 = fmaf(v3.x, e.x, a3); a3 = fmaf(v3.y, e.y, a3);
        a3 = fmaf(v3.z, e.z, a3); a3 = fmaf(v3.w, e.w, a3);
      }
    }
    float dv[4] = {a0, a1, a2, a3};
#pragma unroll
    for (int j = 0; j < 4; ++j) {
      float d = (xsq[qi[j]] + eq) - 2.0f * dv[j];
      u64 p = ((u64)__float_as_uint(d) << 32) | (unsigned)k;
#pragma unroll
      for (int s = 1; s <= 32; s <<= 1) {
        u64 o = __shfl_xor(p, s);
        if (o < p) p = o;
      }
      if (l == 0) atomicMin(&packed2[qi[j]], p);
    }
  }
}

__global__ __launch_bounds__(256) void vq_out(const u64* __restrict__ packed2,
                                              int* __restrict__ out) {
  int n = blockIdx.x * 256 + threadIdx.x;
  if (n < N_Q) out[n] = (int)(unsigned)(packed2[n] & 0xffffffffull);
}

// ===========================================================================
// Fallback (R1, known-pass) if ws too small.
// ===========================================================================
#define TQ 64
#define TK 64
#define R1_NCH 8
#define R1_KCHUNK (N_K / R1_NCH)

__global__ __launch_bounds__(256) void r1_esq(const float* __restrict__ cb,
                                              float* __restrict__ esq) {
  int k = blockIdx.x * blockDim.x + threadIdx.x;
  if (k >= N_K) return;
  const float4* row = reinterpret_cast<const float4*>(cb + (size_t)k * C_DIM);
  float s = 0.f;
#pragma unroll 8
  for (int c4 = 0; c4 < C_DIM / 4; ++c4) {
    float4 v = row[c4];
    s = fmaf(v.x, v.x, s); s = fmaf(v.y, v.y, s);
    s = fmaf(v.z, v.z, s); s = fmaf(v.w, v.w, s);
  }
  esq[k] = s;
}

__global__ __launch_bounds__(256) void r1_main(
    const float* __restrict__ hidden, const float* __restrict__ cb,
    const float* __restrict__ esq, float* __restrict__ ws_d,
    int* __restrict__ ws_k) {
  __shared__ __align__(16) float xs[C_DIM][TQ + 4];
  __shared__ __align__(16) float es[TK][C_DIM + 4];
  __shared__ float xsq_part[4][TQ];
  __shared__ float xsq[TQ];
  __shared__ float red_d[16][TQ];
  __shared__ int red_k[16][TQ];
  const int tid = threadIdx.x;
  const int q0 = blockIdx.x * TQ;
  const int b = q0 >> 10;
  const int hw0 = q0 & 1023;
  const float* hb = hidden + (size_t)b * (C_DIM * 1024) + hw0;
  for (int idx = tid; idx < C_DIM * TQ; idx += 256) {
    int c = idx >> 6, q = idx & 63;
    xs[c][q] = hb[c * 1024 + q];
  }
  __syncthreads();
  {
    int q = tid & 63, part = tid >> 6, cbase = part * 64;
    float s = 0.f;
    for (int c = 0; c < 64; ++c) { float v = xs[cbase + c][q]; s = fmaf(v, v, s); }
    xsq_part[part][q] = s;
  }
  __syncthreads();
  if (tid < TQ)
    xsq[tid] = ((xsq_part[0][tid] + xsq_part[1][tid]) + xsq_part[2][tid]) + xsq_part[3][tid];
  __syncthreads();
  const int qt = tid & 15, kt = tid >> 4;
  float xsq_r[4];
#pragma unroll
  for (int i = 0; i < 4; ++i) xsq_r[i] = xsq[qt * 4 + i];
  float bd[4]; int bk[4];
#pragma unroll
  for (int i = 0; i < 4; ++i) { bd[i] = 3.4e38f; bk[i] = 0x7fffffff; }
  const int kbegin = blockIdx.y * R1_KCHUNK;
  for (int kt0 = kbegin; kt0 < kbegin + R1_KCHUNK; kt0 += TK) {
    __syncthreads();
    for (int idx = tid; idx < TK * (C_DIM / 4); idx += 256) {
      int kk = idx >> 6, c4 = idx & 63;
      float4 v = reinterpret_cast<const float4*>(cb + (size_t)(kt0 + kk) * C_DIM)[c4];
      es[kk][c4 * 4 + 0] = v.x; es[kk][c4 * 4 + 1] = v.y;
      es[kk][c4 * 4 + 2] = v.z; es[kk][c4 * 4 + 3] = v.w;
    }
    __syncthreads();
    float acc[4][4];
#pragma unroll
    for (int i = 0; i < 4; ++i)
#pragma unroll
      for (int j = 0; j < 4; ++j) acc[i][j] = 0.f;
    for (int c4 = 0; c4 < C_DIM; c4 += 4) {
      float4 xv0 = *reinterpret_cast<const float4*>(&xs[c4 + 0][qt * 4]);
      float4 xv1 = *reinterpret_cast<const float4*>(&xs[c4 + 1][qt * 4]);
      float4 xv2 = *reinterpret_cast<const float4*>(&xs[c4 + 2][qt * 4]);
      float4 xv3 = *reinterpret_cast<const float4*>(&xs[c4 + 3][qt * 4]);
      float xq0[4] = {xv0.x, xv0.y, xv0.z, xv0.w};
      float xq1[4] = {xv1.x, xv1.y, xv1.z, xv1.w};
      float xq2[4] = {xv2.x, xv2.y, xv2.z, xv2.w};
      float xq3[4] = {xv3.x, xv3.y, xv3.z, xv3.w};
      float4 ev[4];
#pragma unroll
      for (int j = 0; j < 4; ++j)
        ev[j] = *reinterpret_cast<const float4*>(&es[kt * 4 + j][c4]);
#pragma unroll
      for (int i = 0; i < 4; ++i) {
#pragma unroll
        for (int j = 0; j < 4; ++j) {
          float a = acc[i][j];
          a = fmaf(xq0[i], ev[j].x, a);
          a = fmaf(xq1[i], ev[j].y, a);
          a = fmaf(xq2[i], ev[j].z, a);
          a = fmaf(xq3[i], ev[j].w, a);
          acc[i][j] = a;
        }
      }
    }
#pragma unroll
    for (int j = 0; j < 4; ++j) {
      int k = kt0 + kt * 4 + j;
      float eq = esq[k];
#pragma unroll
      for (int i = 0; i < 4; ++i) {
        float t1 = xsq_r[i] + eq;
        float d = t1 - 2.0f * acc[i][j];
        if (d < bd[i]) { bd[i] = d; bk[i] = k; }
      }
    }
  }
#pragma unroll
  for (int i = 0; i < 4; ++i) {
    red_d[kt][qt * 4 + i] = bd[i];
    red_k[kt][qt * 4 + i] = bk[i];
  }
  __syncthreads();
  if (tid < TQ) {
    float d = red_d[0][tid]; int kb = red_k[0][tid];
    for (int t = 1; t < 16; ++t) {
      float dn = red_d[t][tid]; int kn = red_k[t][tid];
      if (dn < d || (dn == d && kn < kb)) { d = dn; kb = kn; }
    }
    int q = q0 + tid;
    ws_d[(size_t)q * R1_NCH + blockIdx.y] = d;
    ws_k[(size_t)q * R1_NCH + blockIdx.y] = kb;
  }
}

__global__ __launch_bounds__(256) void r1_final(
    const float* __restrict__ ws_d, const int* __restrict__ ws_k,
    int* __restrict__ out) {
  int n = blockIdx.x * blockDim.x + threadIdx.x;
  if (n >= N_Q) return;
  const float* dp = ws_d + (size_t)n * R1_NCH;
  const int* kp = ws_k + (size_t)n * R1_NCH;
  float d = dp[0]; int kb = kp[0];
#pragma unroll
  for (int j = 1; j < R1_NCH; ++j) {
    float dn = dp[j]; int kn = kp[j];
    if (dn < d || (dn == d && kn < kb)) { d = dn; kb = kn; }
  }
  out[n] = kb;
}

extern "C" void kernel_launch(void* const* d_in, const int* in_sizes, int n_in,
                              void* d_out, int out_size, void* d_ws,
                              size_t ws_size, hipStream_t stream) {
  const float* hidden = (const float*)d_in[0];
  const float* cb = (const float*)d_in[1];
  int* out = (int*)d_out;

  const size_t MB = 1024 * 1024;
  const size_t NEED_FULL = 45 * MB;   // with transposed codebook ct
  const size_t NEED_MID = 29 * MB;    // without ct (R8-proven budget)

  if (ws_size >= NEED_MID) {
    const bool full = ws_size >= NEED_FULL;
    char* w = (char*)d_ws;
    unsigned short* xb = (unsigned short*)(w);                 // 4MB
    unsigned short* eb = (unsigned short*)(w + 4 * MB);        // 8MB
    float* xt = (float*)(w + 12 * MB);                         // 8MB
    float* ct = full ? (float*)(w + 20 * MB) : nullptr;        // 16MB
    float* mins_t = (float*)(w + (full ? 36 : 20) * MB);       // 8MB [g][q]
    char* s = w + (full ? 44 : 28) * MB;
    float* xsq = (float*)(s);                                  // 32KB
    float* esq = (float*)(s + 65536);                          // 64KB
    float* thr = (float*)(s + 131072);                         // 32KB
    u64* packed2 = (u64*)(s + 196608);                         // 64KB

    vq_pre_x<<<dim3(128), dim3(256), 0, stream>>>(hidden, xt, xb, xsq, packed2);
    vq_pre_e<<<dim3(N_K / 64), dim3(256), 0, stream>>>(cb, eb, esq, ct);
    vq_gemm<<<dim3((N_Q / BM) * (N_K / BN)), dim3(512), 0, stream>>>(
        xb, eb, xsq, esq, mins_t);
    vq_thr<<<dim3(N_Q / 256), dim3(256), 0, stream>>>(mins_t, thr);
    vq_rescore_s<<<dim3(NGRAN, RQS), dim3(256), 0, stream>>>(
        xt, cb, ct, xsq, esq, mins_t, thr, packed2);
    vq_out<<<dim3(N_Q / 256), dim3(256), 0, stream>>>(packed2, out);
  } else {
    float* esq_f = (float*)d_ws;
    float* ws_d = (float*)((char*)d_ws + 65536);
    int* ws_k = (int*)((char*)d_ws + 65536 + N_Q * R1_NCH * 4);
    r1_esq<<<dim3(N_K / 256), dim3(256), 0, stream>>>(cb, esq_f);
    r1_main<<<dim3(N_Q / TQ, R1_NCH), dim3(256), 0, stream>>>(hidden, cb, esq_f, ws_d, ws_k);
    r1_final<<<dim3(N_Q / 256), dim3(256), 0, stream>>>(ws_d, ws_k, out);
  }
}